// Round 7
// baseline (13690.814 us; speedup 1.0000x reference)
//
#include <hip/hip_runtime.h>
#include <stdint.h>

// RevGRU encoder, MI355X.
// R13: R12 (4-hop, sentinel gates, coalesced col-major channels; 7.35ms) with
// serialization-event reduction:
//  (1) fragment-direct phases: each GEMM computed full-K by one wave per 16-col
//      tile (z: waves 0-3 = z1, 4-7 = z2; g: waves 0,1 = g1, 4,5 = g2), with
//      sigmoid/tanh/h-update applied directly on MFMA accumulator fragments
//      (row lq*4+i, col lm). Removes the redbuf write+barrier+read from all 4
//      phases. Weight regs shared via single wgt[24]/wgtg[16] arrays (~160 VGPR).
//  (2) per-wave sentinels: producing wave drains its own stores (inline
//      s_waitcnt vmcnt(0)) and lane0 stores a wave-sentinel; consumers poll
//      8WG x {4,2} slots. Inter-WG signal no longer waits for a WG barrier.
// Barriers/step 16 -> 8. Protocol (tags, gate ordering) unchanged from R8/R12.

typedef __attribute__((ext_vector_type(8))) short short8;
typedef __attribute__((ext_vector_type(4))) float floatx4;
typedef unsigned long long ull;

#define MFMA16(a,b,c) __builtin_amdgcn_mfma_f32_16x16x32_bf16((a),(b),(c),0,0,0)
#define DRAIN() asm volatile("s_waitcnt vmcnt(0)" ::: "memory")

__device__ __forceinline__ short bf16_rne(float f) {
  uint32_t u = __float_as_uint(f);
  u += 0x7FFFu + ((u >> 16) & 1u);
  return (short)(u >> 16);
}
__device__ __forceinline__ float bf16f(short s) {
  return __uint_as_float(((uint32_t)(uint16_t)s) << 16);
}
__device__ __forceinline__ void st64(ull* p, ull v) {
  __hip_atomic_store(p, v, __ATOMIC_RELAXED, __HIP_MEMORY_SCOPE_AGENT);
}
__device__ __forceinline__ ull ld64(const ull* p) {
  return __hip_atomic_load(p, __ATOMIC_RELAXED, __HIP_MEMORY_SCOPE_AGENT);
}

#define SCALE_F 8388608.0f
#define INV_S   (1.0f/8388608.0f)

// ---- static device scratch ----
__device__ float g_X[50331648];            // X0: 32768 x 1536
__device__ short g_WTh[2][786432];
__device__ short g_WTl[2][786432];
__device__ float g_biasL[2][1536];
__device__ ull g_ch[2][4][6][4096];        // channels, COL-MAJOR [col*16+row]
__device__ ull g_h0s[16777216];            // [t][col512][row64] tagged {tag, f32}
__device__ ull g_x1r[3145728];             // ring [t&31][row][1536] tagged {tag, f32}
__device__ ull g_sw[2][4][4][8][4];        // wave sentinels [L][dm][phase][cg][slot]
__device__ unsigned g_epoch;

__global__ void bump_epoch() { g_epoch = g_epoch + 1u; }

// ------------------------------------------------------------------
__global__ void prep_x(const float* __restrict__ Wz1, const float* __restrict__ bz1,
                       const float* __restrict__ Wg1, const float* __restrict__ bg1,
                       const float* __restrict__ Wz2, const float* __restrict__ bz2,
                       const float* __restrict__ Wg2, const float* __restrict__ bg2,
                       int layer, int* __restrict__ d_out, int zero_extra) {
  int idx = blockIdx.x * 256 + threadIdx.x;
  int k = idx / 1536;
  int c = idx - k * 1536;
  const float* W; const float* bb; int cc; int ncols;
  if (c < 512)       { W = Wz1; bb = bz1; cc = c;        ncols = 512; }
  else if (c < 768)  { W = Wg1; bb = bg1; cc = c - 512;  ncols = 256; }
  else if (c < 1280) { W = Wz2; bb = bz2; cc = c - 768;  ncols = 512; }
  else               { W = Wg2; bb = bg2; cc = c - 1280; ncols = 256; }
  float wv = W[(size_t)layer * 768 * ncols + (size_t)k * ncols + cc];
  short hi = bf16_rne(wv);
  short lo = bf16_rne(wv - bf16f(hi));
  g_WTh[layer][(size_t)c * 512 + k] = hi;
  g_WTl[layer][(size_t)c * 512 + k] = lo;
  if (k == 0) g_biasL[layer][c] = bb[layer * ncols + cc];
  if (zero_extra && idx < 6400) d_out[65536 + idx] = 0;
}

// ------------------------------------------------------------------
__global__ __launch_bounds__(256)
void gemmx_kernel(const int* __restrict__ seq, const float* __restrict__ emb) {
  __shared__ float At[128][36];
  __shared__ short Bhi[128][40];
  __shared__ short Blo[128][40];
  __shared__ int toks[128];
  int tid = threadIdx.x;
  int r0 = blockIdx.x * 128;
  int c0 = blockIdx.y * 128;
  if (tid < 128) toks[tid] = seq[r0 + tid];
  int lane = tid & 63;
  int wid = tid >> 6;
  int wm = wid & 1, wn = wid >> 1;
  int lm = lane & 15, lq = lane >> 4;
  floatx4 zero4 = {0.f, 0.f, 0.f, 0.f};
  floatx4 acc[4][4];
#pragma unroll
  for (int a = 0; a < 4; ++a)
#pragma unroll
    for (int b = 0; b < 4; ++b) acc[a][b] = zero4;
  __syncthreads();
  int am = tid >> 1;
  int ah = (tid & 1) * 16;
  const float* arow = emb + (size_t)toks[am] * 512;
  const short* bh_base = g_WTh[0] + (size_t)(c0 + am) * 512;
  const short* bl_base = g_WTl[0] + (size_t)(c0 + am) * 512;
  for (int kb = 0; kb < 16; ++kb) {
    int k0 = kb * 32 + ah;
    float4 a0 = *(const float4*)(arow + k0);
    float4 a1 = *(const float4*)(arow + k0 + 4);
    float4 a2 = *(const float4*)(arow + k0 + 8);
    float4 a3 = *(const float4*)(arow + k0 + 12);
    short4 b0 = *(const short4*)(bh_base + k0);
    short4 b1 = *(const short4*)(bh_base + k0 + 4);
    short4 b2 = *(const short4*)(bh_base + k0 + 8);
    short4 b3 = *(const short4*)(bh_base + k0 + 12);
    short4 l0 = *(const short4*)(bl_base + k0);
    short4 l1 = *(const short4*)(bl_base + k0 + 4);
    short4 l2 = *(const short4*)(bl_base + k0 + 8);
    short4 l3 = *(const short4*)(bl_base + k0 + 12);
    __syncthreads();
    *(float4*)&At[am][ah]      = a0;
    *(float4*)&At[am][ah + 4]  = a1;
    *(float4*)&At[am][ah + 8]  = a2;
    *(float4*)&At[am][ah + 12] = a3;
    *(short4*)&Bhi[am][ah]      = b0;
    *(short4*)&Bhi[am][ah + 4]  = b1;
    *(short4*)&Bhi[am][ah + 8]  = b2;
    *(short4*)&Bhi[am][ah + 12] = b3;
    *(short4*)&Blo[am][ah]      = l0;
    *(short4*)&Blo[am][ah + 4]  = l1;
    *(short4*)&Blo[am][ah + 8]  = l2;
    *(short4*)&Blo[am][ah + 12] = l3;
    __syncthreads();
    short8 afh[4], afl[4];
#pragma unroll
    for (int mt = 0; mt < 4; ++mt) {
      const float* ap = &At[wm*64 + mt*16 + lm][lq*8];
#pragma unroll
      for (int j = 0; j < 8; ++j) {
        float v = ap[j];
        short hi = bf16_rne(v);
        afh[mt][j] = hi;
        afl[mt][j] = bf16_rne(v - bf16f(hi));
      }
    }
#pragma unroll
    for (int nt = 0; nt < 4; ++nt) {
      short8 bfh = *(short8*)&Bhi[wn*64 + nt*16 + lm][lq*8];
      short8 bfl = *(short8*)&Blo[wn*64 + nt*16 + lm][lq*8];
#pragma unroll
      for (int mt = 0; mt < 4; ++mt) {
        acc[mt][nt] = MFMA16(afh[mt], bfh, acc[mt][nt]);
        acc[mt][nt] = MFMA16(afl[mt], bfh, acc[mt][nt]);
        acc[mt][nt] = MFMA16(afh[mt], bfl, acc[mt][nt]);
      }
    }
  }
#pragma unroll
  for (int nt = 0; nt < 4; ++nt) {
    int gc = c0 + wn*64 + nt*16 + lm;
    float bv = g_biasL[0][gc];
#pragma unroll
    for (int mt = 0; mt < 4; ++mt) {
#pragma unroll
      for (int i = 0; i < 4; ++i) {
        int gr = r0 + wm*64 + mt*16 + lq*4 + i;
        g_X[(size_t)gr * 1536 + gc] = acc[mt][nt][i] + bv;
      }
    }
  }
}

// ------------------------------------------------------------------
__global__ __launch_bounds__(512, 1)
void fused_kernel(const float* __restrict__ Wz1g, const float* __restrict__ Wg1g,
                  const float* __restrict__ Wz2g, const float* __restrict__ Wg2g,
                  const int* __restrict__ lengths, int* __restrict__ d_out) {
  __shared__ int   h1i[16][260];
  __shared__ int   h2i[16][260];
  __shared__ short phi[16][264];
  __shared__ short pmi[16][264];
  __shared__ short plo[16][264];
  __shared__ int lens[16];
  __shared__ short ahs[16][520];
  __shared__ short als[16][520];

  int tid = threadIdx.x;
  int bid = blockIdx.x;
  int lane = tid & 63, wv = tid >> 6;   // 8 waves
  int lm = lane & 15, lq = lane >> 4;
  unsigned ep = g_epoch;

  if (bid >= 64) {
    // ================== role: X1 producer (48 WGs) ==================
    int xw = bid - 64;
    int r4 = xw & 3;
    int cs = xw >> 2;
    int colx = cs * 128 + wv * 16 + lm;
    short8 bh[16], bl[16];
#pragma unroll
    for (int kf = 0; kf < 16; ++kf) {
      bh[kf] = *(const short8*)&g_WTh[1][(size_t)colx * 512 + kf * 32 + lq * 8];
      bl[kf] = *(const short8*)&g_WTl[1][(size_t)colx * 512 + kf * 32 + lq * 8];
    }
    float bvx = g_biasL[1][colx];

    for (int t = 0; t < 512; ++t) {
      unsigned tagt = (ep << 10) | (unsigned)(t + 1);
      // gate: all 8 L0 WGs of domain r4 finished step t's P4 (2 wave slots each)
      if (tid < 16) {
        const ull* sp = &g_sw[0][r4][3][tid & 7][tid >> 3];
        while ((int)((unsigned)(ld64(sp) >> 32) - tagt) < 0) __builtin_amdgcn_s_sleep(1);
      }
      __syncthreads();
      // stage h0s[t]: thread tid takes col tid, rows r4*16..+16 (128B contiguous)
      {
        const ull* hp = &g_h0s[((size_t)t * 512 + tid) * 64 + r4 * 16];
        ull v[16];
        do { v[0] = ld64(hp); } while ((unsigned)(v[0] >> 32) != tagt);
#pragma unroll
        for (int i = 1; i < 16; ++i) v[i] = ld64(hp + i);
        unsigned pend = 0;
#pragma unroll
        for (int i = 1; i < 16; ++i)
          if ((unsigned)(v[i] >> 32) != tagt) pend |= 1u << i;
        while (pend) {
          __builtin_amdgcn_s_sleep(1);
#pragma unroll
          for (int i = 1; i < 16; ++i)
            if (pend & (1u << i)) {
              v[i] = ld64(hp + i);
              if ((unsigned)(v[i] >> 32) == tagt) pend &= ~(1u << i);
            }
        }
#pragma unroll
        for (int i = 0; i < 16; ++i) {
          float f = __uint_as_float((unsigned)v[i]);
          short hi = bf16_rne(f);
          ahs[i][tid] = hi;
          als[i][tid] = bf16_rne(f - bf16f(hi));
        }
      }
      __syncthreads();
      floatx4 acc = {0.f, 0.f, 0.f, 0.f};
#pragma unroll
      for (int kf = 0; kf < 16; ++kf) {
        short8 a0 = *(short8*)&ahs[lm][kf * 32 + lq * 8];
        short8 a1 = *(short8*)&als[lm][kf * 32 + lq * 8];
        acc = MFMA16(a0, bh[kf], acc);
        acc = MFMA16(a1, bh[kf], acc);
        acc = MFMA16(a0, bl[kf], acc);
      }
      if (t >= 25) {
        if (tid < 4) {
          unsigned need = (ep << 10) | (unsigned)(t - 24);
          while ((unsigned)(ld64(&g_ch[1][tid][5][0]) >> 32) < need) __builtin_amdgcn_s_sleep(2);
        }
      }
      __syncthreads();
#pragma unroll
      for (int i = 0; i < 4; ++i) {
        int row = r4 * 16 + lq * 4 + i;
        st64(&g_x1r[((size_t)(t & 31) * 64 + row) * 1536 + colx],
             ((ull)tagt << 32) | __float_as_uint(acc[i] + bvx));
      }
      __syncthreads();
    }
    return;
  }

  // ================== role: scan (layer L), 32 WGs each ==================
  int grp = bid & 7;
  int cg  = bid >> 3;
  int L   = grp >> 2;
  int dm  = grp & 3;
  int rb0 = dm * 16;
  ull (*ch)[4096] = g_ch[L][dm];

  bool gw = (wv == 0 || wv == 1 || wv == 4 || wv == 5);
  int zt = wv & 3;                       // z tile index 0..3
  int zcol = cg * 64 + zt * 16 + lm;     // z output col in [0,512)
  int zxcol = (wv < 4 ? 0 : 768) + zcol; // x column for this wave's z phase
  int gcolh = cg * 32 + (wv & 1) * 16 + lm;   // h col in [0,256) (g waves)
  int gxcol = (wv < 4 ? 512 : 1280) + gcolh;

  if (tid < 16) lens[tid] = lengths[rb0 + tid];
  for (int i = tid; i < 16 * 260; i += 512) { ((int*)h1i)[i] = 0; ((int*)h2i)[i] = 0; }

  // ---- weights: wgt = z1 (wv<4) or z2 (wv>=4), full K=256, split-3 ----
  //      wgtg = g1 (wv 0,1) or g2 (wv 4,5), full K=256, split-2
  short8 wgt[24], wgtg[16];
  {
    const float* Wz = (wv < 4) ? Wz1g : Wz2g;
    const float* Wp = Wz + (size_t)L * 768 * 512 + (size_t)512 * 512 + zcol;
#pragma unroll
    for (int ks = 0; ks < 8; ++ks) {
      short8 t0, t1, t2;
#pragma unroll
      for (int j = 0; j < 8; ++j) {
        float v = Wp[(size_t)(ks * 32 + lq * 8 + j) * 512] * INV_S;
        short a0 = bf16_rne(v); float r1 = v - bf16f(a0);
        short a1 = bf16_rne(r1);
        t0[j] = a0; t1[j] = a1; t2[j] = bf16_rne(r1 - bf16f(a1));
      }
      wgt[ks * 3 + 0] = t0; wgt[ks * 3 + 1] = t1; wgt[ks * 3 + 2] = t2;
    }
    if (gw) {
      const float* Wg = (wv < 4) ? Wg1g : Wg2g;
      const float* Gp = Wg + (size_t)L * 768 * 256 + (size_t)512 * 256 + gcolh;
#pragma unroll
      for (int ks = 0; ks < 8; ++ks) {
        short8 t0, t1;
#pragma unroll
        for (int j = 0; j < 8; ++j) {
          float v = Gp[(size_t)(ks * 32 + lq * 8 + j) * 256];
          short a0 = bf16_rne(v);
          t0[j] = a0; t1[j] = bf16_rne(v - bf16f(a0));
        }
        wgtg[ks * 2 + 0] = t0; wgtg[ks * 2 + 1] = t1;
      }
    }
  }
  __syncthreads();

  int scc = tid >> 1, sh = (tid & 1) << 3;   // stage mapping: col scc, rows sh..sh+8

  // L0 fragment x values (current + prefetch-next)
  float xzc[4], xgc[4];
  if (L == 0) {
#pragma unroll
    for (int i = 0; i < 4; ++i)
      xzc[i] = g_X[(size_t)(rb0 + lq * 4 + i) * 1536 + zxcol];
    if (gw) {
#pragma unroll
      for (int i = 0; i < 4; ++i)
        xgc[i] = g_X[(size_t)(rb0 + lq * 4 + i) * 1536 + gxcol];
    }
  }

#define GATEW(PH, NS, NEED)                                                    \
  {                                                                            \
    if (tid < 8 * (NS)) {                                                      \
      const ull* sp_ = &g_sw[L][dm][PH][tid & 7][tid >> 3];                    \
      while ((int)((unsigned)(ld64(sp_) >> 32) - (NEED)) < 0)                  \
        __builtin_amdgcn_s_sleep(1);                                           \
    }                                                                          \
    __syncthreads();                                                           \
  }

#define STAGE8(CHIDX, EXP, DEPOSIT)                                            \
  {                                                                            \
    const ull* cp_ = &ch[CHIDX][scc * 16 + sh];                                \
    ull v_[8];                                                                 \
    do { v_[0] = ld64(cp_); } while ((unsigned)(v_[0] >> 32) != (EXP));        \
    _Pragma("unroll")                                                          \
    for (int i_ = 1; i_ < 8; ++i_) v_[i_] = ld64(cp_ + i_);                    \
    unsigned pend_ = 0;                                                        \
    _Pragma("unroll")                                                          \
    for (int i_ = 1; i_ < 8; ++i_)                                             \
      if ((unsigned)(v_[i_] >> 32) != (EXP)) pend_ |= 1u << i_;                \
    while (pend_) {                                                            \
      __builtin_amdgcn_s_sleep(1);                                             \
      _Pragma("unroll")                                                        \
      for (int i_ = 1; i_ < 8; ++i_)                                           \
        if (pend_ & (1u << i_)) {                                              \
          v_[i_] = ld64(cp_ + i_);                                             \
          if ((unsigned)(v_[i_] >> 32) == (EXP)) pend_ &= ~(1u << i_);         \
        }                                                                      \
    }                                                                          \
    _Pragma("unroll")                                                          \
    for (int i_ = 0; i_ < 8; ++i_) { DEPOSIT; }                                \
  }

#define DEP_SPLIT(HARR)                                                        \
  { int hv_ = (int)(unsigned)v_[i_];                                           \
    HARR[sh + i_][scc] = hv_;                                                  \
    float fv_ = (float)hv_;                                                    \
    short a0_ = bf16_rne(fv_); float r1_ = fv_ - bf16f(a0_);                   \
    short a1_ = bf16_rne(r1_);                                                 \
    phi[sh + i_][scc] = a0_; pmi[sh + i_][scc] = a1_;                          \
    plo[sh + i_][scc] = bf16_rne(r1_ - bf16f(a1_)); }

#define DEP_R()                                                                \
  { unsigned pl_ = (unsigned)v_[i_];                                           \
    phi[sh + i_][scc] = (short)(pl_ >> 16);                                    \
    plo[sh + i_][scc] = (short)(pl_ & 0xFFFFu); }

#define SPLIT3Z(SRC)                                                           \
  {                                                                            \
    _Pragma("unroll")                                                          \
    for (int i_ = 0; i_ < 8; ++i_) {                                           \
      float v = (float)SRC[sh + i_][scc];                                      \
      short a0 = bf16_rne(v); float r1 = v - bf16f(a0);                        \
      short a1 = bf16_rne(r1);                                                 \
      phi[sh + i_][scc] = a0; pmi[sh + i_][scc] = a1;                          \
      plo[sh + i_][scc] = bf16_rne(r1 - bf16f(a1));                            \
    }                                                                          \
  }

  for (int t = 0; t < 512; ++t) {
    unsigned tagp = (ep << 10) | (unsigned)(t + 1);

    // L0: prefetch next step's x fragments
    float xzn[4], xgn[4];
    if (L == 0) {
      int tn = (t + 1 < 512) ? t + 1 : t;
#pragma unroll
      for (int i = 0; i < 4; ++i)
        xzn[i] = g_X[(size_t)(tn * 64 + rb0 + lq * 4 + i) * 1536 + zxcol];
      if (gw) {
#pragma unroll
        for (int i = 0; i < 4; ++i)
          xgn[i] = g_X[(size_t)(tn * 64 + rb0 + lq * 4 + i) * 1536 + gxcol];
      }
    }

    // L1: early-issue this step's x1 fragment loads (producers run ahead)
    const ull* pzb = nullptr; const ull* pgb = nullptr;
    ull xzv[4], xgv[4];
    if (L == 1) {
      size_t rbase = (size_t)((t & 31) * 64) + rb0 + lq * 4;
      pzb = &g_x1r[rbase * 1536 + zxcol];
#pragma unroll
      for (int i = 0; i < 4; ++i) xzv[i] = ld64(pzb + (size_t)i * 1536);
      if (gw) {
        pgb = &g_x1r[rbase * 1536 + gxcol];
#pragma unroll
        for (int i = 0; i < 4; ++i) xgv[i] = ld64(pgb + (size_t)i * 1536);
      }
    }
    auto vfy = [&](ull v, const ull* p) -> float {
      while ((unsigned)(v >> 32) != tagp) { __builtin_amdgcn_s_sleep(1); v = ld64(p); }
      return __uint_as_float((unsigned)v);
    };

    // ================= P1: z1 (waves 0..3) =================
    if (t > 0) {
      GATEW(3, 2, (ep << 10) | (unsigned)t);
      STAGE8(5, (ep << 10) | (unsigned)t, DEP_SPLIT(h2i));
    } else {
      SPLIT3Z(h2i);
    }
    __syncthreads();
    if (wv < 4) {
      floatx4 acc = {0.f, 0.f, 0.f, 0.f};
#pragma unroll
      for (int ks = 0; ks < 8; ++ks) {
        int k0 = ks * 32 + lq * 8;
        short8 a0 = *(short8*)&phi[lm][k0];
        short8 a1 = *(short8*)&pmi[lm][k0];
        short8 a2 = *(short8*)&plo[lm][k0];
        acc = MFMA16(a0, wgt[ks*3+0], acc);
        acc = MFMA16(a0, wgt[ks*3+1], acc);
        acc = MFMA16(a1, wgt[ks*3+0], acc);
        acc = MFMA16(a1, wgt[ks*3+1], acc);
        acc = MFMA16(a0, wgt[ks*3+2], acc);
        acc = MFMA16(a2, wgt[ks*3+0], acc);
      }
#pragma unroll
      for (int i = 0; i < 4; ++i) {
        int ri = lq * 4 + i;
        float xv = (L == 0) ? xzc[i] : vfy(xzv[i], pzb + (size_t)i * 1536);
        float s = 1.0f / (1.0f + expf(-(acc[i] + xv)));
        if (zcol < 256) {
          float qf = floorf((0.875f * s + 0.125f) * 1024.0f);
          int qi = (int)qf; qi = qi < 1 ? 1 : (qi > 1024 ? 1024 : qi);
          st64(&ch[0][zcol * 16 + ri], ((ull)tagp << 32) | (unsigned)qi);
        } else {
          int rc = zcol - 256;
          float p = s * ((float)h2i[ri][rc] * INV_S);
          short p0 = bf16_rne(p);
          short p1s = bf16_rne(p - bf16f(p0));
          unsigned pay = ((unsigned)(unsigned short)p0 << 16) | (unsigned)(unsigned short)p1s;
          st64(&ch[1][rc * 16 + ri], ((ull)tagp << 32) | pay);
        }
      }
      DRAIN();
      if (lane == 0) st64(&g_sw[L][dm][0][cg][zt], ((ull)tagp << 32) | 1u);
    }

    // ================= P2: g1 + h1 update (waves 0,1) =================
    GATEW(0, 4, tagp);
    STAGE8(1, tagp, DEP_R());
    __syncthreads();
    if (wv < 2) {
      floatx4 acc = {0.f, 0.f, 0.f, 0.f};
#pragma unroll
      for (int ks = 0; ks < 8; ++ks) {
        int k0 = ks * 32 + lq * 8;
        short8 a0 = *(short8*)&phi[lm][k0];
        short8 a1 = *(short8*)&plo[lm][k0];
        acc = MFMA16(a0, wgtg[ks*2+0], acc);
        acc = MFMA16(a1, wgtg[ks*2+0], acc);
        acc = MFMA16(a0, wgtg[ks*2+1], acc);
      }
      const ull* qp = &ch[0][gcolh * 16 + lq * 4];
      ull q64[4];
#pragma unroll
      for (int i = 0; i < 4; ++i) q64[i] = ld64(qp + i);
#pragma unroll
      for (int i = 0; i < 4; ++i)
        while ((unsigned)(q64[i] >> 32) != tagp) {
          __builtin_amdgcn_s_sleep(1); q64[i] = ld64(qp + i);
        }
#pragma unroll
      for (int i = 0; i < 4; ++i) {
        int ri = lq * 4 + i;
        float xv = (L == 0) ? xgc[i] : vfy(xgv[i], pgb + (size_t)i * 1536);
        float g = tanhf(acc[i] + xv);
        int q = (int)(unsigned)q64[i];
        int hold = h1i[ri][gcolh];
        float zf = (float)q * (1.0f / 1024.0f);
        int ni = (int)rintf((1.0f - zf) * g * SCALE_F);
        int hnew = (hold >> 10) * q + (((hold & 1023) * q) >> 10) + ni;
        if (t >= lens[ri]) hnew = hold;
        h1i[ri][gcolh] = hnew;
        st64(&ch[2][gcolh * 16 + ri], ((ull)tagp << 32) | (unsigned)hnew);
        if (L == 0)
          st64(&g_h0s[((size_t)t * 512 + gcolh) * 64 + rb0 + ri],
               ((ull)tagp << 32) | __float_as_uint((float)hnew * INV_S));
        else if (gcolh < 100) d_out[65536 + (t + 1) * 6400 + (rb0 + ri) * 100 + gcolh] = hnew;
        if (t == 511) d_out[L * 32768 + (rb0 + ri) * 512 + gcolh] = hnew;
      }
      DRAIN();
      if (lane == 0) st64(&g_sw[L][dm][1][cg][wv], ((ull)tagp << 32) | 1u);
    }

    // ================= P3: z2 (waves 4..7) =================
    GATEW(1, 2, tagp);
    STAGE8(2, tagp, DEP_SPLIT(h1i));
    __syncthreads();
    if (wv >= 4) {
      floatx4 acc = {0.f, 0.f, 0.f, 0.f};
#pragma unroll
      for (int ks = 0; ks < 8; ++ks) {
        int k0 = ks * 32 + lq * 8;
        short8 a0 = *(short8*)&phi[lm][k0];
        short8 a1 = *(short8*)&pmi[lm][k0];
        short8 a2 = *(short8*)&plo[lm][k0];
        acc = MFMA16(a0, wgt[ks*3+0], acc);
        acc = MFMA16(a0, wgt[ks*3+1], acc);
        acc = MFMA16(a1, wgt[ks*3+0], acc);
        acc = MFMA16(a1, wgt[ks*3+1], acc);
        acc = MFMA16(a0, wgt[ks*3+2], acc);
        acc = MFMA16(a2, wgt[ks*3+0], acc);
      }
#pragma unroll
      for (int i = 0; i < 4; ++i) {
        int ri = lq * 4 + i;
        float xv = (L == 0) ? xzc[i] : vfy(xzv[i], pzb + (size_t)i * 1536);
        float s = 1.0f / (1.0f + expf(-(acc[i] + xv)));
        if (zcol < 256) {
          float qf = floorf((0.875f * s + 0.125f) * 1024.0f);
          int qi = (int)qf; qi = qi < 1 ? 1 : (qi > 1024 ? 1024 : qi);
          st64(&ch[3][zcol * 16 + ri], ((ull)tagp << 32) | (unsigned)qi);
        } else {
          int rc = zcol - 256;
          float p = s * ((float)h1i[ri][rc] * INV_S);
          short p0 = bf16_rne(p);
          short p1s = bf16_rne(p - bf16f(p0));
          unsigned pay = ((unsigned)(unsigned short)p0 << 16) | (unsigned)(unsigned short)p1s;
          st64(&ch[4][rc * 16 + ri], ((ull)tagp << 32) | pay);
        }
      }
      DRAIN();
      if (lane == 0) st64(&g_sw[L][dm][2][cg][zt], ((ull)tagp << 32) | 1u);
    }

    // ================= P4: g2 + h2 update (waves 4,5) =================
    GATEW(2, 4, tagp);
    STAGE8(4, tagp, DEP_R());
    __syncthreads();
    if (wv == 4 || wv == 5) {
      floatx4 acc = {0.f, 0.f, 0.f, 0.f};
#pragma unroll
      for (int ks = 0; ks < 8; ++ks) {
        int k0 = ks * 32 + lq * 8;
        short8 a0 = *(short8*)&phi[lm][k0];
        short8 a1 = *(short8*)&plo[lm][k0];
        acc = MFMA16(a0, wgtg[ks*2+0], acc);
        acc = MFMA16(a1, wgtg[ks*2+0], acc);
        acc = MFMA16(a0, wgtg[ks*2+1], acc);
      }
      const ull* qp = &ch[3][gcolh * 16 + lq * 4];
      ull q64[4];
#pragma unroll
      for (int i = 0; i < 4; ++i) q64[i] = ld64(qp + i);
#pragma unroll
      for (int i = 0; i < 4; ++i)
        while ((unsigned)(q64[i] >> 32) != tagp) {
          __builtin_amdgcn_s_sleep(1); q64[i] = ld64(qp + i);
        }
#pragma unroll
      for (int i = 0; i < 4; ++i) {
        int ri = lq * 4 + i;
        float xv = (L == 0) ? xgc[i] : vfy(xgv[i], pgb + (size_t)i * 1536);
        float g = tanhf(acc[i] + xv);
        int q = (int)(unsigned)q64[i];
        int hold = h2i[ri][gcolh];
        float zf = (float)q * (1.0f / 1024.0f);
        int ni = (int)rintf((1.0f - zf) * g * SCALE_F);
        int hnew = (hold >> 10) * q + (((hold & 1023) * q) >> 10) + ni;
        if (t >= lens[ri]) hnew = hold;
        h2i[ri][gcolh] = hnew;
        st64(&ch[5][gcolh * 16 + ri], ((ull)tagp << 32) | (unsigned)hnew);
        if (L == 0)
          st64(&g_h0s[((size_t)t * 512 + 256 + gcolh) * 64 + rb0 + ri],
               ((ull)tagp << 32) | __float_as_uint((float)hnew * INV_S));
        if (t == 511) d_out[L * 32768 + (rb0 + ri) * 512 + 256 + gcolh] = hnew;
      }
      DRAIN();
      if (lane == 0) st64(&g_sw[L][dm][3][cg][wv - 4], ((ull)tagp << 32) | 1u);
    }

    if (L == 0) {
#pragma unroll
      for (int i = 0; i < 4; ++i) { xzc[i] = xzn[i]; }
      if (gw) {
#pragma unroll
        for (int i = 0; i < 4; ++i) { xgc[i] = xgn[i]; }
      }
    }
  }
#undef GATEW
#undef STAGE8
#undef DEP_SPLIT
#undef DEP_R
#undef SPLIT3Z
}

// ------------------------------------------------------------------
extern "C" void kernel_launch(void* const* d_in, const int* in_sizes, int n_in,
                              void* d_out, int out_size, void* d_ws, size_t ws_size,
                              hipStream_t stream) {
  const int*   seq     = (const int*)d_in[0];
  const int*   lengths = (const int*)d_in[1];
  const float* emb     = (const float*)d_in[2];
  const float* Wz1     = (const float*)d_in[3];
  const float* bz1     = (const float*)d_in[4];
  const float* Wg1     = (const float*)d_in[5];
  const float* bg1     = (const float*)d_in[6];
  const float* Wz2     = (const float*)d_in[7];
  const float* bz2     = (const float*)d_in[8];
  const float* Wg2     = (const float*)d_in[9];
  const float* bg2     = (const float*)d_in[10];
  int* out = (int*)d_out;
  (void)in_sizes; (void)n_in; (void)out_size; (void)d_ws; (void)ws_size;

  bump_epoch<<<1, 1, 0, stream>>>();
  prep_x<<<3072, 256, 0, stream>>>(Wz1, bz1, Wg1, bg1, Wz2, bz2, Wg2, bg2, 0, out, 1);
  prep_x<<<3072, 256, 0, stream>>>(Wz1, bz1, Wg1, bg1, Wz2, bz2, Wg2, bg2, 1, out, 0);
  gemmx_kernel<<<dim3(256, 12), 256, 0, stream>>>(seq, emb);
  fused_kernel<<<112, 512, 0, stream>>>(Wz1, Wg1, Wz2, Wg2, lengths, out);
}

// Round 8
// 8812.145 us; speedup vs baseline: 1.5536x; 1.5536x over previous
//
#include <hip/hip_runtime.h>
#include <stdint.h>

// RevGRU encoder, MI355X.
// R14: revert R13 (fragment-direct phases doubled serial MFMA per phase and
// DRAIN'd in-flight prefetches; 13.7ms). Back to R12 (4-hop, sentinel gates,
// XCD colocation, coalesced col-major channels; 7.35ms) with one surgical fix:
// POST-GATE BATCH ISSUE. R12's STAGE8 polled value[0] to completion before
// issuing values 1-7, and P2/P4 read q only after the stage finished - each a
// full serial L3 round trip. Post-gate all data is tag-valid by protocol
// (producers drain before sentinel), so issue ALL loads at once (8 stage + q;
// 16 in producer h0s stage); verify loops remain as pure backstop. This is
// R9's batching done after the gate instead of before it (no stale-poll storm).

typedef __attribute__((ext_vector_type(8))) short short8;
typedef __attribute__((ext_vector_type(4))) float floatx4;
typedef unsigned long long ull;

#define MFMA16(a,b,c) __builtin_amdgcn_mfma_f32_16x16x32_bf16((a),(b),(c),0,0,0)

__device__ __forceinline__ short bf16_rne(float f) {
  uint32_t u = __float_as_uint(f);
  u += 0x7FFFu + ((u >> 16) & 1u);
  return (short)(u >> 16);
}
__device__ __forceinline__ float bf16f(short s) {
  return __uint_as_float(((uint32_t)(uint16_t)s) << 16);
}
__device__ __forceinline__ void st64(ull* p, ull v) {
  __hip_atomic_store(p, v, __ATOMIC_RELAXED, __HIP_MEMORY_SCOPE_AGENT);
}
__device__ __forceinline__ ull ld64(const ull* p) {
  return __hip_atomic_load(p, __ATOMIC_RELAXED, __HIP_MEMORY_SCOPE_AGENT);
}

#define SCALE_F 8388608.0f
#define INV_S   (1.0f/8388608.0f)

// ---- static device scratch ----
__device__ float g_X[50331648];            // X0: 32768 x 1536
__device__ short g_WTh[2][786432];
__device__ short g_WTl[2][786432];
__device__ float g_biasL[2][1536];
__device__ ull g_ch[2][4][6][4096];        // channels, COL-MAJOR [col*16+row]
__device__ ull g_h0s[16777216];            // [t][col512][row64] tagged {tag, f32}
__device__ ull g_x1r[3145728];             // ring [t&31][row][1536] tagged {tag, f32}
__device__ ull g_sent[2][4][4][8];         // sentinels [L][dm][phase][cg]
__device__ unsigned g_epoch;

__global__ void bump_epoch() { g_epoch = g_epoch + 1u; }

// ------------------------------------------------------------------
__global__ void prep_x(const float* __restrict__ Wz1, const float* __restrict__ bz1,
                       const float* __restrict__ Wg1, const float* __restrict__ bg1,
                       const float* __restrict__ Wz2, const float* __restrict__ bz2,
                       const float* __restrict__ Wg2, const float* __restrict__ bg2,
                       int layer, int* __restrict__ d_out, int zero_extra) {
  int idx = blockIdx.x * 256 + threadIdx.x;
  int k = idx / 1536;
  int c = idx - k * 1536;
  const float* W; const float* bb; int cc; int ncols;
  if (c < 512)       { W = Wz1; bb = bz1; cc = c;        ncols = 512; }
  else if (c < 768)  { W = Wg1; bb = bg1; cc = c - 512;  ncols = 256; }
  else if (c < 1280) { W = Wz2; bb = bz2; cc = c - 768;  ncols = 512; }
  else               { W = Wg2; bb = bg2; cc = c - 1280; ncols = 256; }
  float wv = W[(size_t)layer * 768 * ncols + (size_t)k * ncols + cc];
  short hi = bf16_rne(wv);
  short lo = bf16_rne(wv - bf16f(hi));
  g_WTh[layer][(size_t)c * 512 + k] = hi;
  g_WTl[layer][(size_t)c * 512 + k] = lo;
  if (k == 0) g_biasL[layer][c] = bb[layer * ncols + cc];
  if (zero_extra && idx < 6400) d_out[65536 + idx] = 0;
}

// ------------------------------------------------------------------
__global__ __launch_bounds__(256)
void gemmx_kernel(const int* __restrict__ seq, const float* __restrict__ emb) {
  __shared__ float At[128][36];
  __shared__ short Bhi[128][40];
  __shared__ short Blo[128][40];
  __shared__ int toks[128];
  int tid = threadIdx.x;
  int r0 = blockIdx.x * 128;
  int c0 = blockIdx.y * 128;
  if (tid < 128) toks[tid] = seq[r0 + tid];
  int lane = tid & 63;
  int wid = tid >> 6;
  int wm = wid & 1, wn = wid >> 1;
  int lm = lane & 15, lq = lane >> 4;
  floatx4 zero4 = {0.f, 0.f, 0.f, 0.f};
  floatx4 acc[4][4];
#pragma unroll
  for (int a = 0; a < 4; ++a)
#pragma unroll
    for (int b = 0; b < 4; ++b) acc[a][b] = zero4;
  __syncthreads();
  int am = tid >> 1;
  int ah = (tid & 1) * 16;
  const float* arow = emb + (size_t)toks[am] * 512;
  const short* bh_base = g_WTh[0] + (size_t)(c0 + am) * 512;
  const short* bl_base = g_WTl[0] + (size_t)(c0 + am) * 512;
  for (int kb = 0; kb < 16; ++kb) {
    int k0 = kb * 32 + ah;
    float4 a0 = *(const float4*)(arow + k0);
    float4 a1 = *(const float4*)(arow + k0 + 4);
    float4 a2 = *(const float4*)(arow + k0 + 8);
    float4 a3 = *(const float4*)(arow + k0 + 12);
    short4 b0 = *(const short4*)(bh_base + k0);
    short4 b1 = *(const short4*)(bh_base + k0 + 4);
    short4 b2 = *(const short4*)(bh_base + k0 + 8);
    short4 b3 = *(const short4*)(bh_base + k0 + 12);
    short4 l0 = *(const short4*)(bl_base + k0);
    short4 l1 = *(const short4*)(bl_base + k0 + 4);
    short4 l2 = *(const short4*)(bl_base + k0 + 8);
    short4 l3 = *(const short4*)(bl_base + k0 + 12);
    __syncthreads();
    *(float4*)&At[am][ah]      = a0;
    *(float4*)&At[am][ah + 4]  = a1;
    *(float4*)&At[am][ah + 8]  = a2;
    *(float4*)&At[am][ah + 12] = a3;
    *(short4*)&Bhi[am][ah]      = b0;
    *(short4*)&Bhi[am][ah + 4]  = b1;
    *(short4*)&Bhi[am][ah + 8]  = b2;
    *(short4*)&Bhi[am][ah + 12] = b3;
    *(short4*)&Blo[am][ah]      = l0;
    *(short4*)&Blo[am][ah + 4]  = l1;
    *(short4*)&Blo[am][ah + 8]  = l2;
    *(short4*)&Blo[am][ah + 12] = l3;
    __syncthreads();
    short8 afh[4], afl[4];
#pragma unroll
    for (int mt = 0; mt < 4; ++mt) {
      const float* ap = &At[wm*64 + mt*16 + lm][lq*8];
#pragma unroll
      for (int j = 0; j < 8; ++j) {
        float v = ap[j];
        short hi = bf16_rne(v);
        afh[mt][j] = hi;
        afl[mt][j] = bf16_rne(v - bf16f(hi));
      }
    }
#pragma unroll
    for (int nt = 0; nt < 4; ++nt) {
      short8 bfh = *(short8*)&Bhi[wn*64 + nt*16 + lm][lq*8];
      short8 bfl = *(short8*)&Blo[wn*64 + nt*16 + lm][lq*8];
#pragma unroll
      for (int mt = 0; mt < 4; ++mt) {
        acc[mt][nt] = MFMA16(afh[mt], bfh, acc[mt][nt]);
        acc[mt][nt] = MFMA16(afl[mt], bfh, acc[mt][nt]);
        acc[mt][nt] = MFMA16(afh[mt], bfl, acc[mt][nt]);
      }
    }
  }
#pragma unroll
  for (int nt = 0; nt < 4; ++nt) {
    int gc = c0 + wn*64 + nt*16 + lm;
    float bv = g_biasL[0][gc];
#pragma unroll
    for (int mt = 0; mt < 4; ++mt) {
#pragma unroll
      for (int i = 0; i < 4; ++i) {
        int gr = r0 + wm*64 + mt*16 + lq*4 + i;
        g_X[(size_t)gr * 1536 + gc] = acc[mt][nt][i] + bv;
      }
    }
  }
}

// ------------------------------------------------------------------
__global__ __launch_bounds__(512, 1)
void fused_kernel(const float* __restrict__ Wz1g, const float* __restrict__ Wg1g,
                  const float* __restrict__ Wz2g, const float* __restrict__ Wg2g,
                  const int* __restrict__ lengths, int* __restrict__ d_out) {
  __shared__ int   h1i[16][260];
  __shared__ int   h2i[16][260];
  __shared__ short phi[16][264];
  __shared__ short pmi[16][264];
  __shared__ short plo[16][264];
  __shared__ float redbuf[2304];
  __shared__ int lens[16];
  __shared__ short ahs[16][520];
  __shared__ short als[16][520];

  int tid = threadIdx.x;
  int bid = blockIdx.x;
  int lane = tid & 63, wv = tid >> 6;   // 8 waves
  int lm = lane & 15, lq = lane >> 4;
  unsigned ep = g_epoch;

  if (bid >= 64) {
    // ================== role: X1 producer (48 WGs) ==================
    int xw = bid - 64;
    int r4 = xw & 3;
    int cs = xw >> 2;
    int colx = cs * 128 + wv * 16 + lm;
    short8 bh[16], bl[16];
#pragma unroll
    for (int kf = 0; kf < 16; ++kf) {
      bh[kf] = *(const short8*)&g_WTh[1][(size_t)colx * 512 + kf * 32 + lq * 8];
      bl[kf] = *(const short8*)&g_WTl[1][(size_t)colx * 512 + kf * 32 + lq * 8];
    }
    float bvx = g_biasL[1][colx];

    for (int t = 0; t < 512; ++t) {
      unsigned tagt = (ep << 10) | (unsigned)(t + 1);
      // gate: all 8 L0 WGs of domain r4 finished step t's P4
      if (tid < 8) {
        const ull* sp = &g_sent[0][r4][3][tid];
        while ((int)((unsigned)(ld64(sp) >> 32) - tagt) < 0) __builtin_amdgcn_s_sleep(1);
      }
      __syncthreads();
      // stage h0s[t]: col tid, rows r4*16..+16 — batch-issue all 16 post-gate
      {
        const ull* hp = &g_h0s[((size_t)t * 512 + tid) * 64 + r4 * 16];
        ull v[16];
#pragma unroll
        for (int i = 0; i < 16; ++i) v[i] = ld64(hp + i);
        unsigned pend = 0;
#pragma unroll
        for (int i = 0; i < 16; ++i)
          if ((unsigned)(v[i] >> 32) != tagt) pend |= 1u << i;
        while (pend) {
          __builtin_amdgcn_s_sleep(1);
#pragma unroll
          for (int i = 0; i < 16; ++i)
            if (pend & (1u << i)) {
              v[i] = ld64(hp + i);
              if ((unsigned)(v[i] >> 32) == tagt) pend &= ~(1u << i);
            }
        }
#pragma unroll
        for (int i = 0; i < 16; ++i) {
          float f = __uint_as_float((unsigned)v[i]);
          short hi = bf16_rne(f);
          ahs[i][tid] = hi;
          als[i][tid] = bf16_rne(f - bf16f(hi));
        }
      }
      __syncthreads();
      floatx4 acc = {0.f, 0.f, 0.f, 0.f};
#pragma unroll
      for (int kf = 0; kf < 16; ++kf) {
        short8 a0 = *(short8*)&ahs[lm][kf * 32 + lq * 8];
        short8 a1 = *(short8*)&als[lm][kf * 32 + lq * 8];
        acc = MFMA16(a0, bh[kf], acc);
        acc = MFMA16(a1, bh[kf], acc);
        acc = MFMA16(a0, bl[kf], acc);
      }
      if (t >= 25) {
        if (tid < 4) {
          unsigned need = (ep << 10) | (unsigned)(t - 24);
          while ((unsigned)(ld64(&g_ch[1][tid][5][0]) >> 32) < need) __builtin_amdgcn_s_sleep(2);
        }
      }
      __syncthreads();
#pragma unroll
      for (int i = 0; i < 4; ++i) {
        int row = r4 * 16 + lq * 4 + i;
        st64(&g_x1r[((size_t)(t & 31) * 64 + row) * 1536 + colx],
             ((ull)tagt << 32) | __float_as_uint(acc[i] + bvx));
      }
      __syncthreads();
    }
    return;
  }

  // ================== role: scan (layer L), 32 WGs each ==================
  // XCD colocation: the 8 cooperating WGs of a (L,dm) group share bid%8.
  int grp = bid & 7;
  int cg  = bid >> 3;
  int L   = grp >> 2;
  int dm  = grp & 3;
  int rb0 = dm * 16;
  ull (*ch)[4096] = g_ch[L][dm];

  if (tid < 16) lens[tid] = lengths[rb0 + tid];
  for (int i = tid; i < 16 * 260; i += 512) { ((int*)h1i)[i] = 0; ((int*)h2i)[i] = 0; }

  // ---- preload recurrent-weight B-frags into registers (split-bf16) ----
  short8 wz1a[4], wz1b[4], wz1c[4], wz2a[4], wz2b[4], wz2c[4];
  short8 wg1a[2], wg1b[2], wg2a[2], wg2b[2];
  {
    int nt = wv & 3, kh = wv >> 2;
    int colz = cg * 64 + nt * 16 + lm;
    const float* W1 = Wz1g + (size_t)L * 768 * 512 + (size_t)512 * 512 + colz;
    const float* W2 = Wz2g + (size_t)L * 768 * 512 + (size_t)512 * 512 + colz;
#pragma unroll
    for (int ks = 0; ks < 4; ++ks) {
      int k0 = kh * 128 + ks * 32 + lq * 8;
      short8 t0, t1, t2, u0, u1, u2;
#pragma unroll
      for (int j = 0; j < 8; ++j) {
        float v = W1[(size_t)(k0 + j) * 512] * INV_S;   // pre-scale: A is raw int h
        short a0 = bf16_rne(v); float r1 = v - bf16f(a0);
        short a1 = bf16_rne(r1); float r2 = r1 - bf16f(a1);
        t0[j] = a0; t1[j] = a1; t2[j] = bf16_rne(r2);
        float v2 = W2[(size_t)(k0 + j) * 512] * INV_S;
        short d0 = bf16_rne(v2); float s1 = v2 - bf16f(d0);
        short d1 = bf16_rne(s1); float s2 = s1 - bf16f(d1);
        u0[j] = d0; u1[j] = d1; u2[j] = bf16_rne(s2);
      }
      wz1a[ks] = t0; wz1b[ks] = t1; wz1c[ks] = t2;
      wz2a[ks] = u0; wz2b[ks] = u1; wz2c[ks] = u2;
    }
    int ntg = wv & 1, kq = wv >> 1;
    int colg = cg * 32 + ntg * 16 + lm;
    const float* G1 = Wg1g + (size_t)L * 768 * 256 + (size_t)512 * 256 + colg;
    const float* G2 = Wg2g + (size_t)L * 768 * 256 + (size_t)512 * 256 + colg;
#pragma unroll
    for (int ks = 0; ks < 2; ++ks) {
      int k0 = kq * 64 + ks * 32 + lq * 8;
      short8 t0, t1, u0, u1;
#pragma unroll
      for (int j = 0; j < 8; ++j) {
        float v = G1[(size_t)(k0 + j) * 256];
        short a0 = bf16_rne(v);
        t0[j] = a0; t1[j] = bf16_rne(v - bf16f(a0));
        float v2 = G2[(size_t)(k0 + j) * 256];
        short d0 = bf16_rne(v2);
        u0[j] = d0; u1[j] = bf16_rne(v2 - bf16f(d0));
      }
      wg1a[ks] = t0; wg1b[ks] = t1; wg2a[ks] = u0; wg2b[ks] = u1;
    }
  }
  __syncthreads();

  int xr = tid & 15, xc = tid >> 4;           // compute mapping
  int scc = tid >> 1, sh = (tid & 1) << 3;    // stage mapping: col scc, rows sh..sh+8

  // x1-ring column offsets (loop-invariant)
  int xo0 = cg * 64 + 2 * xc;          // z1 pair
  int xo1 = 512 + cg * 32 + xc;        // g1
  int xo2 = 768 + cg * 64 + 2 * xc;    // z2 pair
  int xo3 = 1280 + cg * 32 + xc;       // g2

  auto ldx = [&](int tt, float& za, float& zb, float& g1x, float& ya, float& yb, float& g2x) {
    const float* base = g_X + (size_t)(tt * 64 + rb0 + xr) * 1536;
    float2 v1 = *(const float2*)(base + cg * 64 + 2 * xc);
    za = v1.x; zb = v1.y;
    g1x = base[512 + cg * 32 + xc];
    float2 v2 = *(const float2*)(base + 768 + cg * 64 + 2 * xc);
    ya = v2.x; yb = v2.y;
    g2x = base[1280 + cg * 32 + xc];
  };
  float cz1a = 0.f, cz1b = 0.f, cg1x = 0.f, cz2a = 0.f, cz2b = 0.f, cg2x = 0.f;
  if (L == 0) ldx(0, cz1a, cz1b, cg1x, cz2a, cz2b, cg2x);

#define GATE(PH, NEED)                                                         \
  {                                                                            \
    if (tid < 8) {                                                             \
      const ull* sp_ = &g_sent[L][dm][PH][tid];                                \
      while ((int)((unsigned)(ld64(sp_) >> 32) - (NEED)) < 0)                  \
        __builtin_amdgcn_s_sleep(1);                                           \
    }                                                                          \
    __syncthreads();                                                           \
  }

// stage 8 values (post-gate: batch-issue all 8, verify; retry = backstop)
#define STAGE8(CHIDX, EXP, DEPOSIT)                                            \
  {                                                                            \
    const ull* cp_ = &ch[CHIDX][scc * 16 + sh];                                \
    ull v_[8];                                                                 \
    _Pragma("unroll")                                                          \
    for (int i_ = 0; i_ < 8; ++i_) v_[i_] = ld64(cp_ + i_);                    \
    unsigned pend_ = 0;                                                        \
    _Pragma("unroll")                                                          \
    for (int i_ = 0; i_ < 8; ++i_)                                             \
      if ((unsigned)(v_[i_] >> 32) != (EXP)) pend_ |= 1u << i_;                \
    while (pend_) {                                                            \
      __builtin_amdgcn_s_sleep(1);                                             \
      _Pragma("unroll")                                                        \
      for (int i_ = 0; i_ < 8; ++i_)                                           \
        if (pend_ & (1u << i_)) {                                              \
          v_[i_] = ld64(cp_ + i_);                                             \
          if ((unsigned)(v_[i_] >> 32) == (EXP)) pend_ &= ~(1u << i_);         \
        }                                                                      \
    }                                                                          \
    _Pragma("unroll")                                                          \
    for (int i_ = 0; i_ < 8; ++i_) { DEPOSIT; }                                \
  }

#define DEP_SPLIT(HARR)                                                        \
  { int hv_ = (int)(unsigned)v_[i_];                                           \
    HARR[sh + i_][scc] = hv_;                                                  \
    float fv_ = (float)hv_;                                                    \
    short a0_ = bf16_rne(fv_); float r1_ = fv_ - bf16f(a0_);                   \
    short a1_ = bf16_rne(r1_);                                                 \
    phi[sh + i_][scc] = a0_; pmi[sh + i_][scc] = a1_;                          \
    plo[sh + i_][scc] = bf16_rne(r1_ - bf16f(a1_)); }

#define DEP_R()                                                                \
  { unsigned pl_ = (unsigned)v_[i_];                                           \
    phi[sh + i_][scc] = (short)(pl_ >> 16);                                    \
    plo[sh + i_][scc] = (short)(pl_ & 0xFFFFu); }

#define SPLIT3Z(SRC)                                                           \
  {                                                                            \
    _Pragma("unroll")                                                          \
    for (int i_ = 0; i_ < 8; ++i_) {                                           \
      float v = (float)SRC[sh + i_][scc];                                      \
      short a0 = bf16_rne(v); float r1 = v - bf16f(a0);                        \
      short a1 = bf16_rne(r1);                                                 \
      phi[sh + i_][scc] = a0; pmi[sh + i_][scc] = a1;                          \
      plo[sh + i_][scc] = bf16_rne(r1 - bf16f(a1));                            \
    }                                                                          \
  }

  for (int t = 0; t < 512; ++t) {
    unsigned tagp = (ep << 10) | (unsigned)(t + 1);

    float nz1a, nz1b, ng1x, nz2a, nz2b, ng2x;
    if (L == 0) {
      int tn = (t + 1 < 512) ? t + 1 : t;
      ldx(tn, nz1a, nz1b, ng1x, nz2a, nz2b, ng2x);   // prefetch next step's X0
    }

    // L1: issue this step's 6 x1-ring loads early (producers run ahead)
    const ull* xb = nullptr;
    ull x0v = 0, x1v = 0, x2v = 0, x3v = 0, x4v = 0, x5v = 0;
    if (L == 1) {
      xb = &g_x1r[((size_t)((t & 31) * 64) + rb0 + xr) * 1536];
      x0v = ld64(xb + xo0); x1v = ld64(xb + xo0 + 1);
      x2v = ld64(xb + xo1);
      x3v = ld64(xb + xo2); x4v = ld64(xb + xo2 + 1);
      x5v = ld64(xb + xo3);
    }
    auto vfy = [&](ull v, const ull* p) -> float {
      while ((unsigned)(v >> 32) != tagp) { __builtin_amdgcn_s_sleep(1); v = ld64(p); }
      return __uint_as_float((unsigned)v);
    };

    // ================= P1: z1 =================
    if (t > 0) {
      GATE(3, (ep << 10) | (unsigned)t);
      STAGE8(5, (ep << 10) | (unsigned)t, DEP_SPLIT(h2i));
    } else {
      SPLIT3Z(h2i);
    }
    __syncthreads();
    {
      int nt = wv & 3, kh = wv >> 2;
      floatx4 acc = {0.f, 0.f, 0.f, 0.f};
#pragma unroll
      for (int ks = 0; ks < 4; ++ks) {
        int k0 = kh * 128 + ks * 32 + lq * 8;
        short8 a0 = *(short8*)&phi[lm][k0];
        short8 a1 = *(short8*)&pmi[lm][k0];
        short8 a2 = *(short8*)&plo[lm][k0];
        acc = MFMA16(a0, wz1a[ks], acc);
        acc = MFMA16(a0, wz1b[ks], acc);
        acc = MFMA16(a1, wz1a[ks], acc);
        acc = MFMA16(a1, wz1b[ks], acc);
        acc = MFMA16(a0, wz1c[ks], acc);
        acc = MFMA16(a2, wz1a[ks], acc);
      }
#pragma unroll
      for (int i = 0; i < 4; ++i) redbuf[kh * 1088 + (lq * 4 + i) * 68 + nt * 16 + lm] = acc[i];
    }
    __syncthreads();
    {
      if (L == 1) { cz1a = vfy(x0v, xb + xo0); cz1b = vfy(x1v, xb + xo0 + 1); }
#pragma unroll
      for (int u = 0; u < 2; ++u) {
        int cc = 2 * xc + u;
        float pre = redbuf[xr * 68 + cc] + redbuf[1088 + xr * 68 + cc] + (u ? cz1b : cz1a);
        float s = 1.0f / (1.0f + expf(-pre));
        int gcol = cg * 64 + cc;
        if (gcol < 256) {
          float qf = floorf((0.875f * s + 0.125f) * 1024.0f);
          int qi = (int)qf; qi = qi < 1 ? 1 : (qi > 1024 ? 1024 : qi);
          st64(&ch[0][gcol * 16 + xr], ((ull)tagp << 32) | (unsigned)qi);
        } else {
          int rc = gcol - 256;
          float p = s * ((float)h2i[xr][rc] * INV_S);
          short p0 = bf16_rne(p);
          short p1s = bf16_rne(p - bf16f(p0));
          unsigned pay = ((unsigned)(unsigned short)p0 << 16) | (unsigned)(unsigned short)p1s;
          st64(&ch[1][rc * 16 + xr], ((ull)tagp << 32) | pay);
        }
      }
    }
    __syncthreads();   // drain P1 stores
    if (tid == 0) st64(&g_sent[L][dm][0][cg], ((ull)tagp << 32) | 1u);
    GATE(0, tagp);

    // ================= P2: g1 + h1 update =================
    int qv;
    {
      const ull* qp = &ch[0][(cg * 32 + xc) * 16 + xr];
      ull q64 = ld64(qp);            // issue alongside stage loads (post-gate)
      STAGE8(1, tagp, DEP_R());
      while ((unsigned)(q64 >> 32) != tagp) { __builtin_amdgcn_s_sleep(1); q64 = ld64(qp); }
      qv = (int)(unsigned)q64;
    }
    __syncthreads();
    {
      int ntg = wv & 1, kq = wv >> 1;
      floatx4 acc = {0.f, 0.f, 0.f, 0.f};
#pragma unroll
      for (int ks = 0; ks < 2; ++ks) {
        int k0 = kq * 64 + ks * 32 + lq * 8;
        short8 a0 = *(short8*)&phi[lm][k0];
        short8 a1 = *(short8*)&plo[lm][k0];
        acc = MFMA16(a0, wg1a[ks], acc);
        acc = MFMA16(a1, wg1a[ks], acc);
        acc = MFMA16(a0, wg1b[ks], acc);
      }
#pragma unroll
      for (int i = 0; i < 4; ++i) redbuf[kq * 576 + (lq * 4 + i) * 36 + ntg * 16 + lm] = acc[i];
    }
    __syncthreads();
    {
      if (L == 1) cg1x = vfy(x2v, xb + xo1);
      float pre = redbuf[xr * 36 + xc] + redbuf[576 + xr * 36 + xc]
                + redbuf[1152 + xr * 36 + xc] + redbuf[1728 + xr * 36 + xc] + cg1x;
      float g = tanhf(pre);
      int gc = cg * 32 + xc;
      int q = qv;
      int hold = h1i[xr][gc];
      float zf = (float)q * (1.0f / 1024.0f);
      int ni = (int)rintf((1.0f - zf) * g * SCALE_F);
      int hnew = (hold >> 10) * q + (((hold & 1023) * q) >> 10) + ni;
      if (t >= lens[xr]) hnew = hold;
      st64(&ch[2][gc * 16 + xr], ((ull)tagp << 32) | (unsigned)hnew);
      if (L == 0)
        st64(&g_h0s[((size_t)t * 512 + gc) * 64 + rb0 + xr],
             ((ull)tagp << 32) | __float_as_uint((float)hnew * INV_S));
      else if (gc < 100) d_out[65536 + (t + 1) * 6400 + (rb0 + xr) * 100 + gc] = hnew;
      if (t == 511) d_out[L * 32768 + (rb0 + xr) * 512 + gc] = hnew;
    }
    __syncthreads();   // protect h1i old-value reads before P3 staging overwrites
    if (tid == 0) st64(&g_sent[L][dm][1][cg], ((ull)tagp << 32) | 1u);
    GATE(1, tagp);

    // ================= P3: z2 =================
    STAGE8(2, tagp, DEP_SPLIT(h1i));
    __syncthreads();
    {
      int nt = wv & 3, kh = wv >> 2;
      floatx4 acc = {0.f, 0.f, 0.f, 0.f};
#pragma unroll
      for (int ks = 0; ks < 4; ++ks) {
        int k0 = kh * 128 + ks * 32 + lq * 8;
        short8 a0 = *(short8*)&phi[lm][k0];
        short8 a1 = *(short8*)&pmi[lm][k0];
        short8 a2 = *(short8*)&plo[lm][k0];
        acc = MFMA16(a0, wz2a[ks], acc);
        acc = MFMA16(a0, wz2b[ks], acc);
        acc = MFMA16(a1, wz2a[ks], acc);
        acc = MFMA16(a1, wz2b[ks], acc);
        acc = MFMA16(a0, wz2c[ks], acc);
        acc = MFMA16(a2, wz2a[ks], acc);
      }
#pragma unroll
      for (int i = 0; i < 4; ++i) redbuf[kh * 1088 + (lq * 4 + i) * 68 + nt * 16 + lm] = acc[i];
    }
    __syncthreads();
    {
      if (L == 1) { cz2a = vfy(x3v, xb + xo2); cz2b = vfy(x4v, xb + xo2 + 1); }
#pragma unroll
      for (int u = 0; u < 2; ++u) {
        int cc = 2 * xc + u;
        float pre = redbuf[xr * 68 + cc] + redbuf[1088 + xr * 68 + cc] + (u ? cz2b : cz2a);
        float s = 1.0f / (1.0f + expf(-pre));
        int gcol = cg * 64 + cc;
        if (gcol < 256) {
          float qf = floorf((0.875f * s + 0.125f) * 1024.0f);
          int qi = (int)qf; qi = qi < 1 ? 1 : (qi > 1024 ? 1024 : qi);
          st64(&ch[3][gcol * 16 + xr], ((ull)tagp << 32) | (unsigned)qi);
        } else {
          int rc = gcol - 256;
          float p = s * ((float)h1i[xr][rc] * INV_S);
          short p0 = bf16_rne(p);
          short p1s = bf16_rne(p - bf16f(p0));
          unsigned pay = ((unsigned)(unsigned short)p0 << 16) | (unsigned)(unsigned short)p1s;
          st64(&ch[4][rc * 16 + xr], ((ull)tagp << 32) | pay);
        }
      }
    }
    __syncthreads();   // drain P3 stores
    if (tid == 0) st64(&g_sent[L][dm][2][cg], ((ull)tagp << 32) | 1u);
    GATE(2, tagp);

    // ================= P4: g2 + h2 update =================
    int qv2;
    {
      const ull* qp = &ch[3][(cg * 32 + xc) * 16 + xr];
      ull q64 = ld64(qp);            // issue alongside stage loads (post-gate)
      STAGE8(4, tagp, DEP_R());
      while ((unsigned)(q64 >> 32) != tagp) { __builtin_amdgcn_s_sleep(1); q64 = ld64(qp); }
      qv2 = (int)(unsigned)q64;
    }
    __syncthreads();
    {
      int ntg = wv & 1, kq = wv >> 1;
      floatx4 acc = {0.f, 0.f, 0.f, 0.f};
#pragma unroll
      for (int ks = 0; ks < 2; ++ks) {
        int k0 = kq * 64 + ks * 32 + lq * 8;
        short8 a0 = *(short8*)&phi[lm][k0];
        short8 a1 = *(short8*)&plo[lm][k0];
        acc = MFMA16(a0, wg2a[ks], acc);
        acc = MFMA16(a1, wg2a[ks], acc);
        acc = MFMA16(a0, wg2b[ks], acc);
      }
#pragma unroll
      for (int i = 0; i < 4; ++i) redbuf[kq * 576 + (lq * 4 + i) * 36 + ntg * 16 + lm] = acc[i];
    }
    __syncthreads();
    {
      if (L == 1) cg2x = vfy(x5v, xb + xo3);
      float pre = redbuf[xr * 36 + xc] + redbuf[576 + xr * 36 + xc]
                + redbuf[1152 + xr * 36 + xc] + redbuf[1728 + xr * 36 + xc] + cg2x;
      float g = tanhf(pre);
      int gc = cg * 32 + xc;
      int q = qv2;
      int hold = h2i[xr][gc];
      float zf = (float)q * (1.0f / 1024.0f);
      int ni = (int)rintf((1.0f - zf) * g * SCALE_F);
      int hnew = (hold >> 10) * q + (((hold & 1023) * q) >> 10) + ni;
      if (t >= lens[xr]) hnew = hold;
      st64(&ch[5][gc * 16 + xr], ((ull)tagp << 32) | (unsigned)hnew);
      if (L == 0)
        st64(&g_h0s[((size_t)t * 512 + 256 + gc) * 64 + rb0 + xr],
             ((ull)tagp << 32) | __float_as_uint((float)hnew * INV_S));
      if (t == 511) d_out[L * 32768 + (rb0 + xr) * 512 + 256 + gc] = hnew;
    }
    __syncthreads();   // protect h2i old-value reads before next-step P1 staging
    if (tid == 0) st64(&g_sent[L][dm][3][cg], ((ull)tagp << 32) | 1u);

    if (L == 0) {
      cz1a = nz1a; cz1b = nz1b; cg1x = ng1x; cz2a = nz2a; cz2b = nz2b; cg2x = ng2x;
    }
  }
#undef GATE
#undef STAGE8
#undef DEP_SPLIT
#undef DEP_R
#undef SPLIT3Z
}

// ------------------------------------------------------------------
extern "C" void kernel_launch(void* const* d_in, const int* in_sizes, int n_in,
                              void* d_out, int out_size, void* d_ws, size_t ws_size,
                              hipStream_t stream) {
  const int*   seq     = (const int*)d_in[0];
  const int*   lengths = (const int*)d_in[1];
  const float* emb     = (const float*)d_in[2];
  const float* Wz1     = (const float*)d_in[3];
  const float* bz1     = (const float*)d_in[4];
  const float* Wg1     = (const float*)d_in[5];
  const float* bg1     = (const float*)d_in[6];
  const float* Wz2     = (const float*)d_in[7];
  const float* bz2     = (const float*)d_in[8];
  const float* Wg2     = (const float*)d_in[9];
  const float* bg2     = (const float*)d_in[10];
  int* out = (int*)d_out;
  (void)in_sizes; (void)n_in; (void)out_size; (void)d_ws; (void)ws_size;

  bump_epoch<<<1, 1, 0, stream>>>();
  prep_x<<<3072, 256, 0, stream>>>(Wz1, bz1, Wg1, bg1, Wz2, bz2, Wg2, bg2, 0, out, 1);
  prep_x<<<3072, 256, 0, stream>>>(Wz1, bz1, Wg1, bg1, Wz2, bz2, Wg2, bg2, 1, out, 0);
  gemmx_kernel<<<dim3(256, 12), 256, 0, stream>>>(seq, emb);
  fused_kernel<<<112, 512, 0, stream>>>(Wz1, Wg1, Wz2, Wg2, lengths, out);
}

// Round 9
// 7688.689 us; speedup vs baseline: 1.7806x; 1.1461x over previous
//
#include <hip/hip_runtime.h>
#include <stdint.h>

// RevGRU encoder, MI355X.
// R15: exact R12 structure (best proven: 7.35ms rocprof) + ONE single-load
// tweak. R14's post-gate 8-wide batch issue REGRESSED (7.35->8.65): at gate
// release all 8 WGs x 512 threads burst 8-9 loads each at the coherent point;
// R12's poll-v[0]-first acts as a congestion stagger (probe, then 7-wide after
// confirm). Rule (3x confirmed: R7, R9, R14): wide simultaneous bursts at the
// coherent point lose. Kept from R14: q issued as ONE early load before STAGE8
// in P2/P4 (verified after) - removes a serial L3 RT without widening the burst.

typedef __attribute__((ext_vector_type(8))) short short8;
typedef __attribute__((ext_vector_type(4))) float floatx4;
typedef unsigned long long ull;

#define MFMA16(a,b,c) __builtin_amdgcn_mfma_f32_16x16x32_bf16((a),(b),(c),0,0,0)

__device__ __forceinline__ short bf16_rne(float f) {
  uint32_t u = __float_as_uint(f);
  u += 0x7FFFu + ((u >> 16) & 1u);
  return (short)(u >> 16);
}
__device__ __forceinline__ float bf16f(short s) {
  return __uint_as_float(((uint32_t)(uint16_t)s) << 16);
}
__device__ __forceinline__ void st64(ull* p, ull v) {
  __hip_atomic_store(p, v, __ATOMIC_RELAXED, __HIP_MEMORY_SCOPE_AGENT);
}
__device__ __forceinline__ ull ld64(const ull* p) {
  return __hip_atomic_load(p, __ATOMIC_RELAXED, __HIP_MEMORY_SCOPE_AGENT);
}

#define SCALE_F 8388608.0f
#define INV_S   (1.0f/8388608.0f)

// ---- static device scratch ----
__device__ float g_X[50331648];            // X0: 32768 x 1536
__device__ short g_WTh[2][786432];
__device__ short g_WTl[2][786432];
__device__ float g_biasL[2][1536];
__device__ ull g_ch[2][4][6][4096];        // channels, COL-MAJOR [col*16+row]
__device__ ull g_h0s[16777216];            // [t][col512][row64] tagged {tag, f32}
__device__ ull g_x1r[3145728];             // ring [t&31][row][1536] tagged {tag, f32}
__device__ ull g_sent[2][4][4][8];         // sentinels [L][dm][phase][cg]
__device__ unsigned g_epoch;

__global__ void bump_epoch() { g_epoch = g_epoch + 1u; }

// ------------------------------------------------------------------
__global__ void prep_x(const float* __restrict__ Wz1, const float* __restrict__ bz1,
                       const float* __restrict__ Wg1, const float* __restrict__ bg1,
                       const float* __restrict__ Wz2, const float* __restrict__ bz2,
                       const float* __restrict__ Wg2, const float* __restrict__ bg2,
                       int layer, int* __restrict__ d_out, int zero_extra) {
  int idx = blockIdx.x * 256 + threadIdx.x;
  int k = idx / 1536;
  int c = idx - k * 1536;
  const float* W; const float* bb; int cc; int ncols;
  if (c < 512)       { W = Wz1; bb = bz1; cc = c;        ncols = 512; }
  else if (c < 768)  { W = Wg1; bb = bg1; cc = c - 512;  ncols = 256; }
  else if (c < 1280) { W = Wz2; bb = bz2; cc = c - 768;  ncols = 512; }
  else               { W = Wg2; bb = bg2; cc = c - 1280; ncols = 256; }
  float wv = W[(size_t)layer * 768 * ncols + (size_t)k * ncols + cc];
  short hi = bf16_rne(wv);
  short lo = bf16_rne(wv - bf16f(hi));
  g_WTh[layer][(size_t)c * 512 + k] = hi;
  g_WTl[layer][(size_t)c * 512 + k] = lo;
  if (k == 0) g_biasL[layer][c] = bb[layer * ncols + cc];
  if (zero_extra && idx < 6400) d_out[65536 + idx] = 0;
}

// ------------------------------------------------------------------
__global__ __launch_bounds__(256)
void gemmx_kernel(const int* __restrict__ seq, const float* __restrict__ emb) {
  __shared__ float At[128][36];
  __shared__ short Bhi[128][40];
  __shared__ short Blo[128][40];
  __shared__ int toks[128];
  int tid = threadIdx.x;
  int r0 = blockIdx.x * 128;
  int c0 = blockIdx.y * 128;
  if (tid < 128) toks[tid] = seq[r0 + tid];
  int lane = tid & 63;
  int wid = tid >> 6;
  int wm = wid & 1, wn = wid >> 1;
  int lm = lane & 15, lq = lane >> 4;
  floatx4 zero4 = {0.f, 0.f, 0.f, 0.f};
  floatx4 acc[4][4];
#pragma unroll
  for (int a = 0; a < 4; ++a)
#pragma unroll
    for (int b = 0; b < 4; ++b) acc[a][b] = zero4;
  __syncthreads();
  int am = tid >> 1;
  int ah = (tid & 1) * 16;
  const float* arow = emb + (size_t)toks[am] * 512;
  const short* bh_base = g_WTh[0] + (size_t)(c0 + am) * 512;
  const short* bl_base = g_WTl[0] + (size_t)(c0 + am) * 512;
  for (int kb = 0; kb < 16; ++kb) {
    int k0 = kb * 32 + ah;
    float4 a0 = *(const float4*)(arow + k0);
    float4 a1 = *(const float4*)(arow + k0 + 4);
    float4 a2 = *(const float4*)(arow + k0 + 8);
    float4 a3 = *(const float4*)(arow + k0 + 12);
    short4 b0 = *(const short4*)(bh_base + k0);
    short4 b1 = *(const short4*)(bh_base + k0 + 4);
    short4 b2 = *(const short4*)(bh_base + k0 + 8);
    short4 b3 = *(const short4*)(bh_base + k0 + 12);
    short4 l0 = *(const short4*)(bl_base + k0);
    short4 l1 = *(const short4*)(bl_base + k0 + 4);
    short4 l2 = *(const short4*)(bl_base + k0 + 8);
    short4 l3 = *(const short4*)(bl_base + k0 + 12);
    __syncthreads();
    *(float4*)&At[am][ah]      = a0;
    *(float4*)&At[am][ah + 4]  = a1;
    *(float4*)&At[am][ah + 8]  = a2;
    *(float4*)&At[am][ah + 12] = a3;
    *(short4*)&Bhi[am][ah]      = b0;
    *(short4*)&Bhi[am][ah + 4]  = b1;
    *(short4*)&Bhi[am][ah + 8]  = b2;
    *(short4*)&Bhi[am][ah + 12] = b3;
    *(short4*)&Blo[am][ah]      = l0;
    *(short4*)&Blo[am][ah + 4]  = l1;
    *(short4*)&Blo[am][ah + 8]  = l2;
    *(short4*)&Blo[am][ah + 12] = l3;
    __syncthreads();
    short8 afh[4], afl[4];
#pragma unroll
    for (int mt = 0; mt < 4; ++mt) {
      const float* ap = &At[wm*64 + mt*16 + lm][lq*8];
#pragma unroll
      for (int j = 0; j < 8; ++j) {
        float v = ap[j];
        short hi = bf16_rne(v);
        afh[mt][j] = hi;
        afl[mt][j] = bf16_rne(v - bf16f(hi));
      }
    }
#pragma unroll
    for (int nt = 0; nt < 4; ++nt) {
      short8 bfh = *(short8*)&Bhi[wn*64 + nt*16 + lm][lq*8];
      short8 bfl = *(short8*)&Blo[wn*64 + nt*16 + lm][lq*8];
#pragma unroll
      for (int mt = 0; mt < 4; ++mt) {
        acc[mt][nt] = MFMA16(afh[mt], bfh, acc[mt][nt]);
        acc[mt][nt] = MFMA16(afl[mt], bfh, acc[mt][nt]);
        acc[mt][nt] = MFMA16(afh[mt], bfl, acc[mt][nt]);
      }
    }
  }
#pragma unroll
  for (int nt = 0; nt < 4; ++nt) {
    int gc = c0 + wn*64 + nt*16 + lm;
    float bv = g_biasL[0][gc];
#pragma unroll
    for (int mt = 0; mt < 4; ++mt) {
#pragma unroll
      for (int i = 0; i < 4; ++i) {
        int gr = r0 + wm*64 + mt*16 + lq*4 + i;
        g_X[(size_t)gr * 1536 + gc] = acc[mt][nt][i] + bv;
      }
    }
  }
}

// ------------------------------------------------------------------
__global__ __launch_bounds__(512, 1)
void fused_kernel(const float* __restrict__ Wz1g, const float* __restrict__ Wg1g,
                  const float* __restrict__ Wz2g, const float* __restrict__ Wg2g,
                  const int* __restrict__ lengths, int* __restrict__ d_out) {
  __shared__ int   h1i[16][260];
  __shared__ int   h2i[16][260];
  __shared__ short phi[16][264];
  __shared__ short pmi[16][264];
  __shared__ short plo[16][264];
  __shared__ float redbuf[2304];
  __shared__ int lens[16];
  __shared__ short ahs[16][520];
  __shared__ short als[16][520];

  int tid = threadIdx.x;
  int bid = blockIdx.x;
  int lane = tid & 63, wv = tid >> 6;   // 8 waves
  int lm = lane & 15, lq = lane >> 4;
  unsigned ep = g_epoch;

  if (bid >= 64) {
    // ================== role: X1 producer (48 WGs) ==================
    int xw = bid - 64;
    int r4 = xw & 3;
    int cs = xw >> 2;
    int colx = cs * 128 + wv * 16 + lm;
    short8 bh[16], bl[16];
#pragma unroll
    for (int kf = 0; kf < 16; ++kf) {
      bh[kf] = *(const short8*)&g_WTh[1][(size_t)colx * 512 + kf * 32 + lq * 8];
      bl[kf] = *(const short8*)&g_WTl[1][(size_t)colx * 512 + kf * 32 + lq * 8];
    }
    float bvx = g_biasL[1][colx];

    for (int t = 0; t < 512; ++t) {
      unsigned tagt = (ep << 10) | (unsigned)(t + 1);
      // gate: all 8 L0 WGs of domain r4 finished step t's P4
      if (tid < 8) {
        const ull* sp = &g_sent[0][r4][3][tid];
        while ((int)((unsigned)(ld64(sp) >> 32) - tagt) < 0) __builtin_amdgcn_s_sleep(1);
      }
      __syncthreads();
      // stage h0s[t]: col tid, rows r4*16..+16 (first-poll throttle, then 15)
      {
        const ull* hp = &g_h0s[((size_t)t * 512 + tid) * 64 + r4 * 16];
        ull v[16];
        do { v[0] = ld64(hp); } while ((unsigned)(v[0] >> 32) != tagt);
#pragma unroll
        for (int i = 1; i < 16; ++i) v[i] = ld64(hp + i);
        unsigned pend = 0;
#pragma unroll
        for (int i = 1; i < 16; ++i)
          if ((unsigned)(v[i] >> 32) != tagt) pend |= 1u << i;
        while (pend) {
          __builtin_amdgcn_s_sleep(1);
#pragma unroll
          for (int i = 1; i < 16; ++i)
            if (pend & (1u << i)) {
              v[i] = ld64(hp + i);
              if ((unsigned)(v[i] >> 32) == tagt) pend &= ~(1u << i);
            }
        }
#pragma unroll
        for (int i = 0; i < 16; ++i) {
          float f = __uint_as_float((unsigned)v[i]);
          short hi = bf16_rne(f);
          ahs[i][tid] = hi;
          als[i][tid] = bf16_rne(f - bf16f(hi));
        }
      }
      __syncthreads();
      floatx4 acc = {0.f, 0.f, 0.f, 0.f};
#pragma unroll
      for (int kf = 0; kf < 16; ++kf) {
        short8 a0 = *(short8*)&ahs[lm][kf * 32 + lq * 8];
        short8 a1 = *(short8*)&als[lm][kf * 32 + lq * 8];
        acc = MFMA16(a0, bh[kf], acc);
        acc = MFMA16(a1, bh[kf], acc);
        acc = MFMA16(a0, bl[kf], acc);
      }
      if (t >= 25) {
        if (tid < 4) {
          unsigned need = (ep << 10) | (unsigned)(t - 24);
          while ((unsigned)(ld64(&g_ch[1][tid][5][0]) >> 32) < need) __builtin_amdgcn_s_sleep(2);
        }
      }
      __syncthreads();
#pragma unroll
      for (int i = 0; i < 4; ++i) {
        int row = r4 * 16 + lq * 4 + i;
        st64(&g_x1r[((size_t)(t & 31) * 64 + row) * 1536 + colx],
             ((ull)tagt << 32) | __float_as_uint(acc[i] + bvx));
      }
      __syncthreads();
    }
    return;
  }

  // ================== role: scan (layer L), 32 WGs each ==================
  // XCD colocation: the 8 cooperating WGs of a (L,dm) group share bid%8.
  int grp = bid & 7;
  int cg  = bid >> 3;
  int L   = grp >> 2;
  int dm  = grp & 3;
  int rb0 = dm * 16;
  ull (*ch)[4096] = g_ch[L][dm];

  if (tid < 16) lens[tid] = lengths[rb0 + tid];
  for (int i = tid; i < 16 * 260; i += 512) { ((int*)h1i)[i] = 0; ((int*)h2i)[i] = 0; }

  // ---- preload recurrent-weight B-frags into registers (split-bf16) ----
  short8 wz1a[4], wz1b[4], wz1c[4], wz2a[4], wz2b[4], wz2c[4];
  short8 wg1a[2], wg1b[2], wg2a[2], wg2b[2];
  {
    int nt = wv & 3, kh = wv >> 2;
    int colz = cg * 64 + nt * 16 + lm;
    const float* W1 = Wz1g + (size_t)L * 768 * 512 + (size_t)512 * 512 + colz;
    const float* W2 = Wz2g + (size_t)L * 768 * 512 + (size_t)512 * 512 + colz;
#pragma unroll
    for (int ks = 0; ks < 4; ++ks) {
      int k0 = kh * 128 + ks * 32 + lq * 8;
      short8 t0, t1, t2, u0, u1, u2;
#pragma unroll
      for (int j = 0; j < 8; ++j) {
        float v = W1[(size_t)(k0 + j) * 512] * INV_S;   // pre-scale: A is raw int h
        short a0 = bf16_rne(v); float r1 = v - bf16f(a0);
        short a1 = bf16_rne(r1); float r2 = r1 - bf16f(a1);
        t0[j] = a0; t1[j] = a1; t2[j] = bf16_rne(r2);
        float v2 = W2[(size_t)(k0 + j) * 512] * INV_S;
        short d0 = bf16_rne(v2); float s1 = v2 - bf16f(d0);
        short d1 = bf16_rne(s1); float s2 = s1 - bf16f(d1);
        u0[j] = d0; u1[j] = d1; u2[j] = bf16_rne(s2);
      }
      wz1a[ks] = t0; wz1b[ks] = t1; wz1c[ks] = t2;
      wz2a[ks] = u0; wz2b[ks] = u1; wz2c[ks] = u2;
    }
    int ntg = wv & 1, kq = wv >> 1;
    int colg = cg * 32 + ntg * 16 + lm;
    const float* G1 = Wg1g + (size_t)L * 768 * 256 + (size_t)512 * 256 + colg;
    const float* G2 = Wg2g + (size_t)L * 768 * 256 + (size_t)512 * 256 + colg;
#pragma unroll
    for (int ks = 0; ks < 2; ++ks) {
      int k0 = kq * 64 + ks * 32 + lq * 8;
      short8 t0, t1, u0, u1;
#pragma unroll
      for (int j = 0; j < 8; ++j) {
        float v = G1[(size_t)(k0 + j) * 256];
        short a0 = bf16_rne(v);
        t0[j] = a0; t1[j] = bf16_rne(v - bf16f(a0));
        float v2 = G2[(size_t)(k0 + j) * 256];
        short d0 = bf16_rne(v2);
        u0[j] = d0; u1[j] = bf16_rne(v2 - bf16f(d0));
      }
      wg1a[ks] = t0; wg1b[ks] = t1; wg2a[ks] = u0; wg2b[ks] = u1;
    }
  }
  __syncthreads();

  int xr = tid & 15, xc = tid >> 4;           // compute mapping
  int scc = tid >> 1, sh = (tid & 1) << 3;    // stage mapping: col scc, rows sh..sh+8

  // x1-ring column offsets (loop-invariant)
  int xo0 = cg * 64 + 2 * xc;          // z1 pair
  int xo1 = 512 + cg * 32 + xc;        // g1
  int xo2 = 768 + cg * 64 + 2 * xc;    // z2 pair
  int xo3 = 1280 + cg * 32 + xc;       // g2

  auto ldx = [&](int tt, float& za, float& zb, float& g1x, float& ya, float& yb, float& g2x) {
    const float* base = g_X + (size_t)(tt * 64 + rb0 + xr) * 1536;
    float2 v1 = *(const float2*)(base + cg * 64 + 2 * xc);
    za = v1.x; zb = v1.y;
    g1x = base[512 + cg * 32 + xc];
    float2 v2 = *(const float2*)(base + 768 + cg * 64 + 2 * xc);
    ya = v2.x; yb = v2.y;
    g2x = base[1280 + cg * 32 + xc];
  };
  float cz1a = 0.f, cz1b = 0.f, cg1x = 0.f, cz2a = 0.f, cz2b = 0.f, cg2x = 0.f;
  if (L == 0) ldx(0, cz1a, cz1b, cg1x, cz2a, cz2b, cg2x);

#define GATE(PH, NEED)                                                         \
  {                                                                            \
    if (tid < 8) {                                                             \
      const ull* sp_ = &g_sent[L][dm][PH][tid];                                \
      while ((int)((unsigned)(ld64(sp_) >> 32) - (NEED)) < 0)                  \
        __builtin_amdgcn_s_sleep(1);                                           \
    }                                                                          \
    __syncthreads();                                                           \
  }

// stage 8 values: first-poll throttle on v[0], then 7-wide issue (R12 pattern)
#define STAGE8(CHIDX, EXP, DEPOSIT)                                            \
  {                                                                            \
    const ull* cp_ = &ch[CHIDX][scc * 16 + sh];                                \
    ull v_[8];                                                                 \
    do { v_[0] = ld64(cp_); } while ((unsigned)(v_[0] >> 32) != (EXP));        \
    _Pragma("unroll")                                                          \
    for (int i_ = 1; i_ < 8; ++i_) v_[i_] = ld64(cp_ + i_);                    \
    unsigned pend_ = 0;                                                        \
    _Pragma("unroll")                                                          \
    for (int i_ = 1; i_ < 8; ++i_)                                             \
      if ((unsigned)(v_[i_] >> 32) != (EXP)) pend_ |= 1u << i_;                \
    while (pend_) {                                                            \
      __builtin_amdgcn_s_sleep(1);                                             \
      _Pragma("unroll")                                                        \
      for (int i_ = 1; i_ < 8; ++i_)                                           \
        if (pend_ & (1u << i_)) {                                              \
          v_[i_] = ld64(cp_ + i_);                                             \
          if ((unsigned)(v_[i_] >> 32) == (EXP)) pend_ &= ~(1u << i_);         \
        }                                                                      \
    }                                                                          \
    _Pragma("unroll")                                                          \
    for (int i_ = 0; i_ < 8; ++i_) { DEPOSIT; }                                \
  }

#define DEP_SPLIT(HARR)                                                        \
  { int hv_ = (int)(unsigned)v_[i_];                                           \
    HARR[sh + i_][scc] = hv_;                                                  \
    float fv_ = (float)hv_;                                                    \
    short a0_ = bf16_rne(fv_); float r1_ = fv_ - bf16f(a0_);                   \
    short a1_ = bf16_rne(r1_);                                                 \
    phi[sh + i_][scc] = a0_; pmi[sh + i_][scc] = a1_;                          \
    plo[sh + i_][scc] = bf16_rne(r1_ - bf16f(a1_)); }

#define DEP_R()                                                                \
  { unsigned pl_ = (unsigned)v_[i_];                                           \
    phi[sh + i_][scc] = (short)(pl_ >> 16);                                    \
    plo[sh + i_][scc] = (short)(pl_ & 0xFFFFu); }

#define SPLIT3Z(SRC)                                                           \
  {                                                                            \
    _Pragma("unroll")                                                          \
    for (int i_ = 0; i_ < 8; ++i_) {                                           \
      float v = (float)SRC[sh + i_][scc];                                      \
      short a0 = bf16_rne(v); float r1 = v - bf16f(a0);                        \
      short a1 = bf16_rne(r1);                                                 \
      phi[sh + i_][scc] = a0; pmi[sh + i_][scc] = a1;                          \
      plo[sh + i_][scc] = bf16_rne(r1 - bf16f(a1));                            \
    }                                                                          \
  }

  for (int t = 0; t < 512; ++t) {
    unsigned tagp = (ep << 10) | (unsigned)(t + 1);

    float nz1a, nz1b, ng1x, nz2a, nz2b, ng2x;
    if (L == 0) {
      int tn = (t + 1 < 512) ? t + 1 : t;
      ldx(tn, nz1a, nz1b, ng1x, nz2a, nz2b, ng2x);   // prefetch next step's X0
    }

    // L1: issue this step's 6 x1-ring loads early (producers run ahead)
    const ull* xb = nullptr;
    ull x0v = 0, x1v = 0, x2v = 0, x3v = 0, x4v = 0, x5v = 0;
    if (L == 1) {
      xb = &g_x1r[((size_t)((t & 31) * 64) + rb0 + xr) * 1536];
      x0v = ld64(xb + xo0); x1v = ld64(xb + xo0 + 1);
      x2v = ld64(xb + xo1);
      x3v = ld64(xb + xo2); x4v = ld64(xb + xo2 + 1);
      x5v = ld64(xb + xo3);
    }
    auto vfy = [&](ull v, const ull* p) -> float {
      while ((unsigned)(v >> 32) != tagp) { __builtin_amdgcn_s_sleep(1); v = ld64(p); }
      return __uint_as_float((unsigned)v);
    };

    // ================= P1: z1 =================
    if (t > 0) {
      GATE(3, (ep << 10) | (unsigned)t);
      STAGE8(5, (ep << 10) | (unsigned)t, DEP_SPLIT(h2i));
    } else {
      SPLIT3Z(h2i);
    }
    __syncthreads();
    {
      int nt = wv & 3, kh = wv >> 2;
      floatx4 acc = {0.f, 0.f, 0.f, 0.f};
#pragma unroll
      for (int ks = 0; ks < 4; ++ks) {
        int k0 = kh * 128 + ks * 32 + lq * 8;
        short8 a0 = *(short8*)&phi[lm][k0];
        short8 a1 = *(short8*)&pmi[lm][k0];
        short8 a2 = *(short8*)&plo[lm][k0];
        acc = MFMA16(a0, wz1a[ks], acc);
        acc = MFMA16(a0, wz1b[ks], acc);
        acc = MFMA16(a1, wz1a[ks], acc);
        acc = MFMA16(a1, wz1b[ks], acc);
        acc = MFMA16(a0, wz1c[ks], acc);
        acc = MFMA16(a2, wz1a[ks], acc);
      }
#pragma unroll
      for (int i = 0; i < 4; ++i) redbuf[kh * 1088 + (lq * 4 + i) * 68 + nt * 16 + lm] = acc[i];
    }
    __syncthreads();
    {
      if (L == 1) { cz1a = vfy(x0v, xb + xo0); cz1b = vfy(x1v, xb + xo0 + 1); }
#pragma unroll
      for (int u = 0; u < 2; ++u) {
        int cc = 2 * xc + u;
        float pre = redbuf[xr * 68 + cc] + redbuf[1088 + xr * 68 + cc] + (u ? cz1b : cz1a);
        float s = 1.0f / (1.0f + expf(-pre));
        int gcol = cg * 64 + cc;
        if (gcol < 256) {
          float qf = floorf((0.875f * s + 0.125f) * 1024.0f);
          int qi = (int)qf; qi = qi < 1 ? 1 : (qi > 1024 ? 1024 : qi);
          st64(&ch[0][gcol * 16 + xr], ((ull)tagp << 32) | (unsigned)qi);
        } else {
          int rc = gcol - 256;
          float p = s * ((float)h2i[xr][rc] * INV_S);
          short p0 = bf16_rne(p);
          short p1s = bf16_rne(p - bf16f(p0));
          unsigned pay = ((unsigned)(unsigned short)p0 << 16) | (unsigned)(unsigned short)p1s;
          st64(&ch[1][rc * 16 + xr], ((ull)tagp << 32) | pay);
        }
      }
    }
    __syncthreads();   // drain P1 stores
    if (tid == 0) st64(&g_sent[L][dm][0][cg], ((ull)tagp << 32) | 1u);
    GATE(0, tagp);

    // ================= P2: g1 + h1 update =================
    int qv;
    {
      const ull* qp = &ch[0][(cg * 32 + xc) * 16 + xr];
      ull q64 = ld64(qp);            // single early load (post-gate, no burst)
      STAGE8(1, tagp, DEP_R());
      while ((unsigned)(q64 >> 32) != tagp) { __builtin_amdgcn_s_sleep(1); q64 = ld64(qp); }
      qv = (int)(unsigned)q64;
    }
    __syncthreads();
    {
      int ntg = wv & 1, kq = wv >> 1;
      floatx4 acc = {0.f, 0.f, 0.f, 0.f};
#pragma unroll
      for (int ks = 0; ks < 2; ++ks) {
        int k0 = kq * 64 + ks * 32 + lq * 8;
        short8 a0 = *(short8*)&phi[lm][k0];
        short8 a1 = *(short8*)&plo[lm][k0];
        acc = MFMA16(a0, wg1a[ks], acc);
        acc = MFMA16(a1, wg1a[ks], acc);
        acc = MFMA16(a0, wg1b[ks], acc);
      }
#pragma unroll
      for (int i = 0; i < 4; ++i) redbuf[kq * 576 + (lq * 4 + i) * 36 + ntg * 16 + lm] = acc[i];
    }
    __syncthreads();
    {
      if (L == 1) cg1x = vfy(x2v, xb + xo1);
      float pre = redbuf[xr * 36 + xc] + redbuf[576 + xr * 36 + xc]
                + redbuf[1152 + xr * 36 + xc] + redbuf[1728 + xr * 36 + xc] + cg1x;
      float g = tanhf(pre);
      int gc = cg * 32 + xc;
      int q = qv;
      int hold = h1i[xr][gc];
      float zf = (float)q * (1.0f / 1024.0f);
      int ni = (int)rintf((1.0f - zf) * g * SCALE_F);
      int hnew = (hold >> 10) * q + (((hold & 1023) * q) >> 10) + ni;
      if (t >= lens[xr]) hnew = hold;
      st64(&ch[2][gc * 16 + xr], ((ull)tagp << 32) | (unsigned)hnew);
      if (L == 0)
        st64(&g_h0s[((size_t)t * 512 + gc) * 64 + rb0 + xr],
             ((ull)tagp << 32) | __float_as_uint((float)hnew * INV_S));
      else if (gc < 100) d_out[65536 + (t + 1) * 6400 + (rb0 + xr) * 100 + gc] = hnew;
      if (t == 511) d_out[L * 32768 + (rb0 + xr) * 512 + gc] = hnew;
    }
    __syncthreads();   // protect h1i old-value reads before P3 staging overwrites
    if (tid == 0) st64(&g_sent[L][dm][1][cg], ((ull)tagp << 32) | 1u);
    GATE(1, tagp);

    // ================= P3: z2 =================
    STAGE8(2, tagp, DEP_SPLIT(h1i));
    __syncthreads();
    {
      int nt = wv & 3, kh = wv >> 2;
      floatx4 acc = {0.f, 0.f, 0.f, 0.f};
#pragma unroll
      for (int ks = 0; ks < 4; ++ks) {
        int k0 = kh * 128 + ks * 32 + lq * 8;
        short8 a0 = *(short8*)&phi[lm][k0];
        short8 a1 = *(short8*)&pmi[lm][k0];
        short8 a2 = *(short8*)&plo[lm][k0];
        acc = MFMA16(a0, wz2a[ks], acc);
        acc = MFMA16(a0, wz2b[ks], acc);
        acc = MFMA16(a1, wz2a[ks], acc);
        acc = MFMA16(a1, wz2b[ks], acc);
        acc = MFMA16(a0, wz2c[ks], acc);
        acc = MFMA16(a2, wz2a[ks], acc);
      }
#pragma unroll
      for (int i = 0; i < 4; ++i) redbuf[kh * 1088 + (lq * 4 + i) * 68 + nt * 16 + lm] = acc[i];
    }
    __syncthreads();
    {
      if (L == 1) { cz2a = vfy(x3v, xb + xo2); cz2b = vfy(x4v, xb + xo2 + 1); }
#pragma unroll
      for (int u = 0; u < 2; ++u) {
        int cc = 2 * xc + u;
        float pre = redbuf[xr * 68 + cc] + redbuf[1088 + xr * 68 + cc] + (u ? cz2b : cz2a);
        float s = 1.0f / (1.0f + expf(-pre));
        int gcol = cg * 64 + cc;
        if (gcol < 256) {
          float qf = floorf((0.875f * s + 0.125f) * 1024.0f);
          int qi = (int)qf; qi = qi < 1 ? 1 : (qi > 1024 ? 1024 : qi);
          st64(&ch[3][gcol * 16 + xr], ((ull)tagp << 32) | (unsigned)qi);
        } else {
          int rc = gcol - 256;
          float p = s * ((float)h1i[xr][rc] * INV_S);
          short p0 = bf16_rne(p);
          short p1s = bf16_rne(p - bf16f(p0));
          unsigned pay = ((unsigned)(unsigned short)p0 << 16) | (unsigned)(unsigned short)p1s;
          st64(&ch[4][rc * 16 + xr], ((ull)tagp << 32) | pay);
        }
      }
    }
    __syncthreads();   // drain P3 stores
    if (tid == 0) st64(&g_sent[L][dm][2][cg], ((ull)tagp << 32) | 1u);
    GATE(2, tagp);

    // ================= P4: g2 + h2 update =================
    int qv2;
    {
      const ull* qp = &ch[3][(cg * 32 + xc) * 16 + xr];
      ull q64 = ld64(qp);            // single early load (post-gate, no burst)
      STAGE8(4, tagp, DEP_R());
      while ((unsigned)(q64 >> 32) != tagp) { __builtin_amdgcn_s_sleep(1); q64 = ld64(qp); }
      qv2 = (int)(unsigned)q64;
    }
    __syncthreads();
    {
      int ntg = wv & 1, kq = wv >> 1;
      floatx4 acc = {0.f, 0.f, 0.f, 0.f};
#pragma unroll
      for (int ks = 0; ks < 2; ++ks) {
        int k0 = kq * 64 + ks * 32 + lq * 8;
        short8 a0 = *(short8*)&phi[lm][k0];
        short8 a1 = *(short8*)&plo[lm][k0];
        acc = MFMA16(a0, wg2a[ks], acc);
        acc = MFMA16(a1, wg2a[ks], acc);
        acc = MFMA16(a0, wg2b[ks], acc);
      }
#pragma unroll
      for (int i = 0; i < 4; ++i) redbuf[kq * 576 + (lq * 4 + i) * 36 + ntg * 16 + lm] = acc[i];
    }
    __syncthreads();
    {
      if (L == 1) cg2x = vfy(x5v, xb + xo3);
      float pre = redbuf[xr * 36 + xc] + redbuf[576 + xr * 36 + xc]
                + redbuf[1152 + xr * 36 + xc] + redbuf[1728 + xr * 36 + xc] + cg2x;
      float g = tanhf(pre);
      int gc = cg * 32 + xc;
      int q = qv2;
      int hold = h2i[xr][gc];
      float zf = (float)q * (1.0f / 1024.0f);
      int ni = (int)rintf((1.0f - zf) * g * SCALE_F);
      int hnew = (hold >> 10) * q + (((hold & 1023) * q) >> 10) + ni;
      if (t >= lens[xr]) hnew = hold;
      st64(&ch[5][gc * 16 + xr], ((ull)tagp << 32) | (unsigned)hnew);
      if (L == 0)
        st64(&g_h0s[((size_t)t * 512 + 256 + gc) * 64 + rb0 + xr],
             ((ull)tagp << 32) | __float_as_uint((float)hnew * INV_S));
      if (t == 511) d_out[L * 32768 + (rb0 + xr) * 512 + 256 + gc] = hnew;
    }
    __syncthreads();   // protect h2i old-value reads before next-step P1 staging
    if (tid == 0) st64(&g_sent[L][dm][3][cg], ((ull)tagp << 32) | 1u);

    if (L == 0) {
      cz1a = nz1a; cz1b = nz1b; cg1x = ng1x; cz2a = nz2a; cz2b = nz2b; cg2x = ng2x;
    }
  }
#undef GATE
#undef STAGE8
#undef DEP_SPLIT
#undef DEP_R
#undef SPLIT3Z
}

// ------------------------------------------------------------------
extern "C" void kernel_launch(void* const* d_in, const int* in_sizes, int n_in,
                              void* d_out, int out_size, void* d_ws, size_t ws_size,
                              hipStream_t stream) {
  const int*   seq     = (const int*)d_in[0];
  const int*   lengths = (const int*)d_in[1];
  const float* emb     = (const float*)d_in[2];
  const float* Wz1     = (const float*)d_in[3];
  const float* bz1     = (const float*)d_in[4];
  const float* Wg1     = (const float*)d_in[5];
  const float* bg1     = (const float*)d_in[6];
  const float* Wz2     = (const float*)d_in[7];
  const float* bz2     = (const float*)d_in[8];
  const float* Wg2     = (const float*)d_in[9];
  const float* bg2     = (const float*)d_in[10];
  int* out = (int*)d_out;
  (void)in_sizes; (void)n_in; (void)out_size; (void)d_ws; (void)ws_size;

  bump_epoch<<<1, 1, 0, stream>>>();
  prep_x<<<3072, 256, 0, stream>>>(Wz1, bz1, Wg1, bg1, Wz2, bz2, Wg2, bg2, 0, out, 1);
  prep_x<<<3072, 256, 0, stream>>>(Wz1, bz1, Wg1, bg1, Wz2, bz2, Wg2, bg2, 1, out, 0);
  gemmx_kernel<<<dim3(256, 12), 256, 0, stream>>>(seq, emb);
  fused_kernel<<<112, 512, 0, stream>>>(Wz1, Wg1, Wz2, Wg2, lengths, out);
}

// Round 10
// 7620.810 us; speedup vs baseline: 1.7965x; 1.0089x over previous
//
#include <hip/hip_runtime.h>
#include <stdint.h>

// RevGRU encoder, MI355X.
// R16: R15 (7.4ms; 4-hop, sentinel gates, coalesced col-major channels, early
// x1/q issue) + EAGER SENTINELS. R15's hop chain serialized:
//   stores -> vmcnt-drain barrier -> tid0 sentinel -> visible -> detect -> gather
// The drain+barrier before the sentinel is NOT needed for correctness (per-value
// tags + verify-retry are ground truth; sentinel is only a poll throttle, R8).
// Post the sentinel immediately after the phase's stores are issued; drop the
// explicit drain barriers - GATE's internal barrier takes over all LDS hazard
// protection (audited per phase: P2-h1i/P4-h2i old-reads vs next staging are
// separated by the following GATE's __syncthreads). Removes 4 barriers/step and
// takes the ~0.5us store-drain off the sentinel critical path on all 4 hops.
// Consumer first-poll throttle absorbs the sentinel-ahead-of-data window.

typedef __attribute__((ext_vector_type(8))) short short8;
typedef __attribute__((ext_vector_type(4))) float floatx4;
typedef unsigned long long ull;

#define MFMA16(a,b,c) __builtin_amdgcn_mfma_f32_16x16x32_bf16((a),(b),(c),0,0,0)

__device__ __forceinline__ short bf16_rne(float f) {
  uint32_t u = __float_as_uint(f);
  u += 0x7FFFu + ((u >> 16) & 1u);
  return (short)(u >> 16);
}
__device__ __forceinline__ float bf16f(short s) {
  return __uint_as_float(((uint32_t)(uint16_t)s) << 16);
}
__device__ __forceinline__ void st64(ull* p, ull v) {
  __hip_atomic_store(p, v, __ATOMIC_RELAXED, __HIP_MEMORY_SCOPE_AGENT);
}
__device__ __forceinline__ ull ld64(const ull* p) {
  return __hip_atomic_load(p, __ATOMIC_RELAXED, __HIP_MEMORY_SCOPE_AGENT);
}

#define SCALE_F 8388608.0f
#define INV_S   (1.0f/8388608.0f)

// ---- static device scratch ----
__device__ float g_X[50331648];            // X0: 32768 x 1536
__device__ short g_WTh[2][786432];
__device__ short g_WTl[2][786432];
__device__ float g_biasL[2][1536];
__device__ ull g_ch[2][4][6][4096];        // channels, COL-MAJOR [col*16+row]
__device__ ull g_h0s[16777216];            // [t][col512][row64] tagged {tag, f32}
__device__ ull g_x1r[3145728];             // ring [t&31][row][1536] tagged {tag, f32}
__device__ ull g_sent[2][4][4][8];         // sentinels [L][dm][phase][cg]
__device__ unsigned g_epoch;

__global__ void bump_epoch() { g_epoch = g_epoch + 1u; }

// ------------------------------------------------------------------
__global__ void prep_x(const float* __restrict__ Wz1, const float* __restrict__ bz1,
                       const float* __restrict__ Wg1, const float* __restrict__ bg1,
                       const float* __restrict__ Wz2, const float* __restrict__ bz2,
                       const float* __restrict__ Wg2, const float* __restrict__ bg2,
                       int layer, int* __restrict__ d_out, int zero_extra) {
  int idx = blockIdx.x * 256 + threadIdx.x;
  int k = idx / 1536;
  int c = idx - k * 1536;
  const float* W; const float* bb; int cc; int ncols;
  if (c < 512)       { W = Wz1; bb = bz1; cc = c;        ncols = 512; }
  else if (c < 768)  { W = Wg1; bb = bg1; cc = c - 512;  ncols = 256; }
  else if (c < 1280) { W = Wz2; bb = bz2; cc = c - 768;  ncols = 512; }
  else               { W = Wg2; bb = bg2; cc = c - 1280; ncols = 256; }
  float wv = W[(size_t)layer * 768 * ncols + (size_t)k * ncols + cc];
  short hi = bf16_rne(wv);
  short lo = bf16_rne(wv - bf16f(hi));
  g_WTh[layer][(size_t)c * 512 + k] = hi;
  g_WTl[layer][(size_t)c * 512 + k] = lo;
  if (k == 0) g_biasL[layer][c] = bb[layer * ncols + cc];
  if (zero_extra && idx < 6400) d_out[65536 + idx] = 0;
}

// ------------------------------------------------------------------
__global__ __launch_bounds__(256)
void gemmx_kernel(const int* __restrict__ seq, const float* __restrict__ emb) {
  __shared__ float At[128][36];
  __shared__ short Bhi[128][40];
  __shared__ short Blo[128][40];
  __shared__ int toks[128];
  int tid = threadIdx.x;
  int r0 = blockIdx.x * 128;
  int c0 = blockIdx.y * 128;
  if (tid < 128) toks[tid] = seq[r0 + tid];
  int lane = tid & 63;
  int wid = tid >> 6;
  int wm = wid & 1, wn = wid >> 1;
  int lm = lane & 15, lq = lane >> 4;
  floatx4 zero4 = {0.f, 0.f, 0.f, 0.f};
  floatx4 acc[4][4];
#pragma unroll
  for (int a = 0; a < 4; ++a)
#pragma unroll
    for (int b = 0; b < 4; ++b) acc[a][b] = zero4;
  __syncthreads();
  int am = tid >> 1;
  int ah = (tid & 1) * 16;
  const float* arow = emb + (size_t)toks[am] * 512;
  const short* bh_base = g_WTh[0] + (size_t)(c0 + am) * 512;
  const short* bl_base = g_WTl[0] + (size_t)(c0 + am) * 512;
  for (int kb = 0; kb < 16; ++kb) {
    int k0 = kb * 32 + ah;
    float4 a0 = *(const float4*)(arow + k0);
    float4 a1 = *(const float4*)(arow + k0 + 4);
    float4 a2 = *(const float4*)(arow + k0 + 8);
    float4 a3 = *(const float4*)(arow + k0 + 12);
    short4 b0 = *(const short4*)(bh_base + k0);
    short4 b1 = *(const short4*)(bh_base + k0 + 4);
    short4 b2 = *(const short4*)(bh_base + k0 + 8);
    short4 b3 = *(const short4*)(bh_base + k0 + 12);
    short4 l0 = *(const short4*)(bl_base + k0);
    short4 l1 = *(const short4*)(bl_base + k0 + 4);
    short4 l2 = *(const short4*)(bl_base + k0 + 8);
    short4 l3 = *(const short4*)(bl_base + k0 + 12);
    __syncthreads();
    *(float4*)&At[am][ah]      = a0;
    *(float4*)&At[am][ah + 4]  = a1;
    *(float4*)&At[am][ah + 8]  = a2;
    *(float4*)&At[am][ah + 12] = a3;
    *(short4*)&Bhi[am][ah]      = b0;
    *(short4*)&Bhi[am][ah + 4]  = b1;
    *(short4*)&Bhi[am][ah + 8]  = b2;
    *(short4*)&Bhi[am][ah + 12] = b3;
    *(short4*)&Blo[am][ah]      = l0;
    *(short4*)&Blo[am][ah + 4]  = l1;
    *(short4*)&Blo[am][ah + 8]  = l2;
    *(short4*)&Blo[am][ah + 12] = l3;
    __syncthreads();
    short8 afh[4], afl[4];
#pragma unroll
    for (int mt = 0; mt < 4; ++mt) {
      const float* ap = &At[wm*64 + mt*16 + lm][lq*8];
#pragma unroll
      for (int j = 0; j < 8; ++j) {
        float v = ap[j];
        short hi = bf16_rne(v);
        afh[mt][j] = hi;
        afl[mt][j] = bf16_rne(v - bf16f(hi));
      }
    }
#pragma unroll
    for (int nt = 0; nt < 4; ++nt) {
      short8 bfh = *(short8*)&Bhi[wn*64 + nt*16 + lm][lq*8];
      short8 bfl = *(short8*)&Blo[wn*64 + nt*16 + lm][lq*8];
#pragma unroll
      for (int mt = 0; mt < 4; ++mt) {
        acc[mt][nt] = MFMA16(afh[mt], bfh, acc[mt][nt]);
        acc[mt][nt] = MFMA16(afl[mt], bfh, acc[mt][nt]);
        acc[mt][nt] = MFMA16(afh[mt], bfl, acc[mt][nt]);
      }
    }
  }
#pragma unroll
  for (int nt = 0; nt < 4; ++nt) {
    int gc = c0 + wn*64 + nt*16 + lm;
    float bv = g_biasL[0][gc];
#pragma unroll
    for (int mt = 0; mt < 4; ++mt) {
#pragma unroll
      for (int i = 0; i < 4; ++i) {
        int gr = r0 + wm*64 + mt*16 + lq*4 + i;
        g_X[(size_t)gr * 1536 + gc] = acc[mt][nt][i] + bv;
      }
    }
  }
}

// ------------------------------------------------------------------
__global__ __launch_bounds__(512, 1)
void fused_kernel(const float* __restrict__ Wz1g, const float* __restrict__ Wg1g,
                  const float* __restrict__ Wz2g, const float* __restrict__ Wg2g,
                  const int* __restrict__ lengths, int* __restrict__ d_out) {
  __shared__ int   h1i[16][260];
  __shared__ int   h2i[16][260];
  __shared__ short phi[16][264];
  __shared__ short pmi[16][264];
  __shared__ short plo[16][264];
  __shared__ float redbuf[2304];
  __shared__ int lens[16];
  __shared__ short ahs[16][520];
  __shared__ short als[16][520];

  int tid = threadIdx.x;
  int bid = blockIdx.x;
  int lane = tid & 63, wv = tid >> 6;   // 8 waves
  int lm = lane & 15, lq = lane >> 4;
  unsigned ep = g_epoch;

  if (bid >= 64) {
    // ================== role: X1 producer (48 WGs) ==================
    int xw = bid - 64;
    int r4 = xw & 3;
    int cs = xw >> 2;
    int colx = cs * 128 + wv * 16 + lm;
    short8 bh[16], bl[16];
#pragma unroll
    for (int kf = 0; kf < 16; ++kf) {
      bh[kf] = *(const short8*)&g_WTh[1][(size_t)colx * 512 + kf * 32 + lq * 8];
      bl[kf] = *(const short8*)&g_WTl[1][(size_t)colx * 512 + kf * 32 + lq * 8];
    }
    float bvx = g_biasL[1][colx];

    for (int t = 0; t < 512; ++t) {
      unsigned tagt = (ep << 10) | (unsigned)(t + 1);
      // gate: all 8 L0 WGs of domain r4 finished step t's P4
      if (tid < 8) {
        const ull* sp = &g_sent[0][r4][3][tid];
        while ((int)((unsigned)(ld64(sp) >> 32) - tagt) < 0) __builtin_amdgcn_s_sleep(1);
      }
      __syncthreads();
      // stage h0s[t]: col tid, rows r4*16..+16 (first-poll throttle, then 15)
      {
        const ull* hp = &g_h0s[((size_t)t * 512 + tid) * 64 + r4 * 16];
        ull v[16];
        do { v[0] = ld64(hp); } while ((unsigned)(v[0] >> 32) != tagt);
#pragma unroll
        for (int i = 1; i < 16; ++i) v[i] = ld64(hp + i);
        unsigned pend = 0;
#pragma unroll
        for (int i = 1; i < 16; ++i)
          if ((unsigned)(v[i] >> 32) != tagt) pend |= 1u << i;
        while (pend) {
          __builtin_amdgcn_s_sleep(1);
#pragma unroll
          for (int i = 1; i < 16; ++i)
            if (pend & (1u << i)) {
              v[i] = ld64(hp + i);
              if ((unsigned)(v[i] >> 32) == tagt) pend &= ~(1u << i);
            }
        }
#pragma unroll
        for (int i = 0; i < 16; ++i) {
          float f = __uint_as_float((unsigned)v[i]);
          short hi = bf16_rne(f);
          ahs[i][tid] = hi;
          als[i][tid] = bf16_rne(f - bf16f(hi));
        }
      }
      __syncthreads();
      floatx4 acc = {0.f, 0.f, 0.f, 0.f};
#pragma unroll
      for (int kf = 0; kf < 16; ++kf) {
        short8 a0 = *(short8*)&ahs[lm][kf * 32 + lq * 8];
        short8 a1 = *(short8*)&als[lm][kf * 32 + lq * 8];
        acc = MFMA16(a0, bh[kf], acc);
        acc = MFMA16(a1, bh[kf], acc);
        acc = MFMA16(a0, bl[kf], acc);
      }
      if (t >= 25) {
        if (tid < 4) {
          unsigned need = (ep << 10) | (unsigned)(t - 24);
          while ((unsigned)(ld64(&g_ch[1][tid][5][0]) >> 32) < need) __builtin_amdgcn_s_sleep(2);
        }
      }
      __syncthreads();
#pragma unroll
      for (int i = 0; i < 4; ++i) {
        int row = r4 * 16 + lq * 4 + i;
        st64(&g_x1r[((size_t)(t & 31) * 64 + row) * 1536 + colx],
             ((ull)tagt << 32) | __float_as_uint(acc[i] + bvx));
      }
      __syncthreads();
    }
    return;
  }

  // ================== role: scan (layer L), 32 WGs each ==================
  // XCD colocation: the 8 cooperating WGs of a (L,dm) group share bid%8.
  int grp = bid & 7;
  int cg  = bid >> 3;
  int L   = grp >> 2;
  int dm  = grp & 3;
  int rb0 = dm * 16;
  ull (*ch)[4096] = g_ch[L][dm];

  if (tid < 16) lens[tid] = lengths[rb0 + tid];
  for (int i = tid; i < 16 * 260; i += 512) { ((int*)h1i)[i] = 0; ((int*)h2i)[i] = 0; }

  // ---- preload recurrent-weight B-frags into registers (split-bf16) ----
  short8 wz1a[4], wz1b[4], wz1c[4], wz2a[4], wz2b[4], wz2c[4];
  short8 wg1a[2], wg1b[2], wg2a[2], wg2b[2];
  {
    int nt = wv & 3, kh = wv >> 2;
    int colz = cg * 64 + nt * 16 + lm;
    const float* W1 = Wz1g + (size_t)L * 768 * 512 + (size_t)512 * 512 + colz;
    const float* W2 = Wz2g + (size_t)L * 768 * 512 + (size_t)512 * 512 + colz;
#pragma unroll
    for (int ks = 0; ks < 4; ++ks) {
      int k0 = kh * 128 + ks * 32 + lq * 8;
      short8 t0, t1, t2, u0, u1, u2;
#pragma unroll
      for (int j = 0; j < 8; ++j) {
        float v = W1[(size_t)(k0 + j) * 512] * INV_S;   // pre-scale: A is raw int h
        short a0 = bf16_rne(v); float r1 = v - bf16f(a0);
        short a1 = bf16_rne(r1); float r2 = r1 - bf16f(a1);
        t0[j] = a0; t1[j] = a1; t2[j] = bf16_rne(r2);
        float v2 = W2[(size_t)(k0 + j) * 512] * INV_S;
        short d0 = bf16_rne(v2); float s1 = v2 - bf16f(d0);
        short d1 = bf16_rne(s1); float s2 = s1 - bf16f(d1);
        u0[j] = d0; u1[j] = d1; u2[j] = bf16_rne(s2);
      }
      wz1a[ks] = t0; wz1b[ks] = t1; wz1c[ks] = t2;
      wz2a[ks] = u0; wz2b[ks] = u1; wz2c[ks] = u2;
    }
    int ntg = wv & 1, kq = wv >> 1;
    int colg = cg * 32 + ntg * 16 + lm;
    const float* G1 = Wg1g + (size_t)L * 768 * 256 + (size_t)512 * 256 + colg;
    const float* G2 = Wg2g + (size_t)L * 768 * 256 + (size_t)512 * 256 + colg;
#pragma unroll
    for (int ks = 0; ks < 2; ++ks) {
      int k0 = kq * 64 + ks * 32 + lq * 8;
      short8 t0, t1, u0, u1;
#pragma unroll
      for (int j = 0; j < 8; ++j) {
        float v = G1[(size_t)(k0 + j) * 256];
        short a0 = bf16_rne(v);
        t0[j] = a0; t1[j] = bf16_rne(v - bf16f(a0));
        float v2 = G2[(size_t)(k0 + j) * 256];
        short d0 = bf16_rne(v2);
        u0[j] = d0; u1[j] = bf16_rne(v2 - bf16f(d0));
      }
      wg1a[ks] = t0; wg1b[ks] = t1; wg2a[ks] = u0; wg2b[ks] = u1;
    }
  }
  __syncthreads();

  int xr = tid & 15, xc = tid >> 4;           // compute mapping
  int scc = tid >> 1, sh = (tid & 1) << 3;    // stage mapping: col scc, rows sh..sh+8

  // x1-ring column offsets (loop-invariant)
  int xo0 = cg * 64 + 2 * xc;          // z1 pair
  int xo1 = 512 + cg * 32 + xc;        // g1
  int xo2 = 768 + cg * 64 + 2 * xc;    // z2 pair
  int xo3 = 1280 + cg * 32 + xc;       // g2

  auto ldx = [&](int tt, float& za, float& zb, float& g1x, float& ya, float& yb, float& g2x) {
    const float* base = g_X + (size_t)(tt * 64 + rb0 + xr) * 1536;
    float2 v1 = *(const float2*)(base + cg * 64 + 2 * xc);
    za = v1.x; zb = v1.y;
    g1x = base[512 + cg * 32 + xc];
    float2 v2 = *(const float2*)(base + 768 + cg * 64 + 2 * xc);
    ya = v2.x; yb = v2.y;
    g2x = base[1280 + cg * 32 + xc];
  };
  float cz1a = 0.f, cz1b = 0.f, cg1x = 0.f, cz2a = 0.f, cz2b = 0.f, cg2x = 0.f;
  if (L == 0) ldx(0, cz1a, cz1b, cg1x, cz2a, cz2b, cg2x);

#define GATE(PH, NEED)                                                         \
  {                                                                            \
    if (tid < 8) {                                                             \
      const ull* sp_ = &g_sent[L][dm][PH][tid];                                \
      while ((int)((unsigned)(ld64(sp_) >> 32) - (NEED)) < 0)                  \
        __builtin_amdgcn_s_sleep(1);                                           \
    }                                                                          \
    __syncthreads();                                                           \
  }

// stage 8 values: first-poll throttle on v[0], then 7-wide issue (R12 pattern)
#define STAGE8(CHIDX, EXP, DEPOSIT)                                            \
  {                                                                            \
    const ull* cp_ = &ch[CHIDX][scc * 16 + sh];                                \
    ull v_[8];                                                                 \
    do { v_[0] = ld64(cp_); } while ((unsigned)(v_[0] >> 32) != (EXP));        \
    _Pragma("unroll")                                                          \
    for (int i_ = 1; i_ < 8; ++i_) v_[i_] = ld64(cp_ + i_);                    \
    unsigned pend_ = 0;                                                        \
    _Pragma("unroll")                                                          \
    for (int i_ = 1; i_ < 8; ++i_)                                             \
      if ((unsigned)(v_[i_] >> 32) != (EXP)) pend_ |= 1u << i_;                \
    while (pend_) {                                                            \
      __builtin_amdgcn_s_sleep(1);                                             \
      _Pragma("unroll")                                                        \
      for (int i_ = 1; i_ < 8; ++i_)                                           \
        if (pend_ & (1u << i_)) {                                              \
          v_[i_] = ld64(cp_ + i_);                                             \
          if ((unsigned)(v_[i_] >> 32) == (EXP)) pend_ &= ~(1u << i_);         \
        }                                                                      \
    }                                                                          \
    _Pragma("unroll")                                                          \
    for (int i_ = 0; i_ < 8; ++i_) { DEPOSIT; }                                \
  }

#define DEP_SPLIT(HARR)                                                        \
  { int hv_ = (int)(unsigned)v_[i_];                                           \
    HARR[sh + i_][scc] = hv_;                                                  \
    float fv_ = (float)hv_;                                                    \
    short a0_ = bf16_rne(fv_); float r1_ = fv_ - bf16f(a0_);                   \
    short a1_ = bf16_rne(r1_);                                                 \
    phi[sh + i_][scc] = a0_; pmi[sh + i_][scc] = a1_;                          \
    plo[sh + i_][scc] = bf16_rne(r1_ - bf16f(a1_)); }

#define DEP_R()                                                                \
  { unsigned pl_ = (unsigned)v_[i_];                                           \
    phi[sh + i_][scc] = (short)(pl_ >> 16);                                    \
    plo[sh + i_][scc] = (short)(pl_ & 0xFFFFu); }

#define SPLIT3Z(SRC)                                                           \
  {                                                                            \
    _Pragma("unroll")                                                          \
    for (int i_ = 0; i_ < 8; ++i_) {                                           \
      float v = (float)SRC[sh + i_][scc];                                      \
      short a0 = bf16_rne(v); float r1 = v - bf16f(a0);                        \
      short a1 = bf16_rne(r1);                                                 \
      phi[sh + i_][scc] = a0; pmi[sh + i_][scc] = a1;                          \
      plo[sh + i_][scc] = bf16_rne(r1 - bf16f(a1));                            \
    }                                                                          \
  }

  for (int t = 0; t < 512; ++t) {
    unsigned tagp = (ep << 10) | (unsigned)(t + 1);

    float nz1a, nz1b, ng1x, nz2a, nz2b, ng2x;
    if (L == 0) {
      int tn = (t + 1 < 512) ? t + 1 : t;
      ldx(tn, nz1a, nz1b, ng1x, nz2a, nz2b, ng2x);   // prefetch next step's X0
    }

    // L1: issue this step's 6 x1-ring loads early (producers run ahead)
    const ull* xb = nullptr;
    ull x0v = 0, x1v = 0, x2v = 0, x3v = 0, x4v = 0, x5v = 0;
    if (L == 1) {
      xb = &g_x1r[((size_t)((t & 31) * 64) + rb0 + xr) * 1536];
      x0v = ld64(xb + xo0); x1v = ld64(xb + xo0 + 1);
      x2v = ld64(xb + xo1);
      x3v = ld64(xb + xo2); x4v = ld64(xb + xo2 + 1);
      x5v = ld64(xb + xo3);
    }
    auto vfy = [&](ull v, const ull* p) -> float {
      while ((unsigned)(v >> 32) != tagp) { __builtin_amdgcn_s_sleep(1); v = ld64(p); }
      return __uint_as_float((unsigned)v);
    };

    // ================= P1: z1 =================
    if (t > 0) {
      GATE(3, (ep << 10) | (unsigned)t);
      STAGE8(5, (ep << 10) | (unsigned)t, DEP_SPLIT(h2i));
    } else {
      SPLIT3Z(h2i);
    }
    __syncthreads();
    {
      int nt = wv & 3, kh = wv >> 2;
      floatx4 acc = {0.f, 0.f, 0.f, 0.f};
#pragma unroll
      for (int ks = 0; ks < 4; ++ks) {
        int k0 = kh * 128 + ks * 32 + lq * 8;
        short8 a0 = *(short8*)&phi[lm][k0];
        short8 a1 = *(short8*)&pmi[lm][k0];
        short8 a2 = *(short8*)&plo[lm][k0];
        acc = MFMA16(a0, wz1a[ks], acc);
        acc = MFMA16(a0, wz1b[ks], acc);
        acc = MFMA16(a1, wz1a[ks], acc);
        acc = MFMA16(a1, wz1b[ks], acc);
        acc = MFMA16(a0, wz1c[ks], acc);
        acc = MFMA16(a2, wz1a[ks], acc);
      }
#pragma unroll
      for (int i = 0; i < 4; ++i) redbuf[kh * 1088 + (lq * 4 + i) * 68 + nt * 16 + lm] = acc[i];
    }
    __syncthreads();
    {
      if (L == 1) { cz1a = vfy(x0v, xb + xo0); cz1b = vfy(x1v, xb + xo0 + 1); }
#pragma unroll
      for (int u = 0; u < 2; ++u) {
        int cc = 2 * xc + u;
        float pre = redbuf[xr * 68 + cc] + redbuf[1088 + xr * 68 + cc] + (u ? cz1b : cz1a);
        float s = 1.0f / (1.0f + expf(-pre));
        int gcol = cg * 64 + cc;
        if (gcol < 256) {
          float qf = floorf((0.875f * s + 0.125f) * 1024.0f);
          int qi = (int)qf; qi = qi < 1 ? 1 : (qi > 1024 ? 1024 : qi);
          st64(&ch[0][gcol * 16 + xr], ((ull)tagp << 32) | (unsigned)qi);
        } else {
          int rc = gcol - 256;
          float p = s * ((float)h2i[xr][rc] * INV_S);
          short p0 = bf16_rne(p);
          short p1s = bf16_rne(p - bf16f(p0));
          unsigned pay = ((unsigned)(unsigned short)p0 << 16) | (unsigned)(unsigned short)p1s;
          st64(&ch[1][rc * 16 + xr], ((ull)tagp << 32) | pay);
        }
      }
    }
    // EAGER sentinel: posted at store-issue, not after drain; value tags are
    // the correctness backstop. GATE(0)'s barrier takes over hazard protection.
    if (tid == 0) st64(&g_sent[L][dm][0][cg], ((ull)tagp << 32) | 1u);
    GATE(0, tagp);

    // ================= P2: g1 + h1 update =================
    int qv;
    {
      const ull* qp = &ch[0][(cg * 32 + xc) * 16 + xr];
      ull q64 = ld64(qp);            // single early load (post-gate, no burst)
      STAGE8(1, tagp, DEP_R());
      while ((unsigned)(q64 >> 32) != tagp) { __builtin_amdgcn_s_sleep(1); q64 = ld64(qp); }
      qv = (int)(unsigned)q64;
    }
    __syncthreads();
    {
      int ntg = wv & 1, kq = wv >> 1;
      floatx4 acc = {0.f, 0.f, 0.f, 0.f};
#pragma unroll
      for (int ks = 0; ks < 2; ++ks) {
        int k0 = kq * 64 + ks * 32 + lq * 8;
        short8 a0 = *(short8*)&phi[lm][k0];
        short8 a1 = *(short8*)&plo[lm][k0];
        acc = MFMA16(a0, wg1a[ks], acc);
        acc = MFMA16(a1, wg1a[ks], acc);
        acc = MFMA16(a0, wg1b[ks], acc);
      }
#pragma unroll
      for (int i = 0; i < 4; ++i) redbuf[kq * 576 + (lq * 4 + i) * 36 + ntg * 16 + lm] = acc[i];
    }
    __syncthreads();
    {
      if (L == 1) cg1x = vfy(x2v, xb + xo1);
      float pre = redbuf[xr * 36 + xc] + redbuf[576 + xr * 36 + xc]
                + redbuf[1152 + xr * 36 + xc] + redbuf[1728 + xr * 36 + xc] + cg1x;
      float g = tanhf(pre);
      int gc = cg * 32 + xc;
      int q = qv;
      int hold = h1i[xr][gc];
      float zf = (float)q * (1.0f / 1024.0f);
      int ni = (int)rintf((1.0f - zf) * g * SCALE_F);
      int hnew = (hold >> 10) * q + (((hold & 1023) * q) >> 10) + ni;
      if (t >= lens[xr]) hnew = hold;
      st64(&ch[2][gc * 16 + xr], ((ull)tagp << 32) | (unsigned)hnew);
      if (L == 0)
        st64(&g_h0s[((size_t)t * 512 + gc) * 64 + rb0 + xr],
             ((ull)tagp << 32) | __float_as_uint((float)hnew * INV_S));
      else if (gc < 100) d_out[65536 + (t + 1) * 6400 + (rb0 + xr) * 100 + gc] = hnew;
      if (t == 511) d_out[L * 32768 + (rb0 + xr) * 512 + gc] = hnew;
    }
    // EAGER sentinel; GATE(1)'s barrier protects h1i old-reads vs P3 staging.
    if (tid == 0) st64(&g_sent[L][dm][1][cg], ((ull)tagp << 32) | 1u);
    GATE(1, tagp);

    // ================= P3: z2 =================
    STAGE8(2, tagp, DEP_SPLIT(h1i));
    __syncthreads();
    {
      int nt = wv & 3, kh = wv >> 2;
      floatx4 acc = {0.f, 0.f, 0.f, 0.f};
#pragma unroll
      for (int ks = 0; ks < 4; ++ks) {
        int k0 = kh * 128 + ks * 32 + lq * 8;
        short8 a0 = *(short8*)&phi[lm][k0];
        short8 a1 = *(short8*)&pmi[lm][k0];
        short8 a2 = *(short8*)&plo[lm][k0];
        acc = MFMA16(a0, wz2a[ks], acc);
        acc = MFMA16(a0, wz2b[ks], acc);
        acc = MFMA16(a1, wz2a[ks], acc);
        acc = MFMA16(a1, wz2b[ks], acc);
        acc = MFMA16(a0, wz2c[ks], acc);
        acc = MFMA16(a2, wz2a[ks], acc);
      }
#pragma unroll
      for (int i = 0; i < 4; ++i) redbuf[kh * 1088 + (lq * 4 + i) * 68 + nt * 16 + lm] = acc[i];
    }
    __syncthreads();
    {
      if (L == 1) { cz2a = vfy(x3v, xb + xo2); cz2b = vfy(x4v, xb + xo2 + 1); }
#pragma unroll
      for (int u = 0; u < 2; ++u) {
        int cc = 2 * xc + u;
        float pre = redbuf[xr * 68 + cc] + redbuf[1088 + xr * 68 + cc] + (u ? cz2b : cz2a);
        float s = 1.0f / (1.0f + expf(-pre));
        int gcol = cg * 64 + cc;
        if (gcol < 256) {
          float qf = floorf((0.875f * s + 0.125f) * 1024.0f);
          int qi = (int)qf; qi = qi < 1 ? 1 : (qi > 1024 ? 1024 : qi);
          st64(&ch[3][gcol * 16 + xr], ((ull)tagp << 32) | (unsigned)qi);
        } else {
          int rc = gcol - 256;
          float p = s * ((float)h1i[xr][rc] * INV_S);
          short p0 = bf16_rne(p);
          short p1s = bf16_rne(p - bf16f(p0));
          unsigned pay = ((unsigned)(unsigned short)p0 << 16) | (unsigned)(unsigned short)p1s;
          st64(&ch[4][rc * 16 + xr], ((ull)tagp << 32) | pay);
        }
      }
    }
    // EAGER sentinel; GATE(2)'s barrier takes over.
    if (tid == 0) st64(&g_sent[L][dm][2][cg], ((ull)tagp << 32) | 1u);
    GATE(2, tagp);

    // ================= P4: g2 + h2 update =================
    int qv2;
    {
      const ull* qp = &ch[3][(cg * 32 + xc) * 16 + xr];
      ull q64 = ld64(qp);            // single early load (post-gate, no burst)
      STAGE8(4, tagp, DEP_R());
      while ((unsigned)(q64 >> 32) != tagp) { __builtin_amdgcn_s_sleep(1); q64 = ld64(qp); }
      qv2 = (int)(unsigned)q64;
    }
    __syncthreads();
    {
      int ntg = wv & 1, kq = wv >> 1;
      floatx4 acc = {0.f, 0.f, 0.f, 0.f};
#pragma unroll
      for (int ks = 0; ks < 2; ++ks) {
        int k0 = kq * 64 + ks * 32 + lq * 8;
        short8 a0 = *(short8*)&phi[lm][k0];
        short8 a1 = *(short8*)&plo[lm][k0];
        acc = MFMA16(a0, wg2a[ks], acc);
        acc = MFMA16(a1, wg2a[ks], acc);
        acc = MFMA16(a0, wg2b[ks], acc);
      }
#pragma unroll
      for (int i = 0; i < 4; ++i) redbuf[kq * 576 + (lq * 4 + i) * 36 + ntg * 16 + lm] = acc[i];
    }
    __syncthreads();
    {
      if (L == 1) cg2x = vfy(x5v, xb + xo3);
      float pre = redbuf[xr * 36 + xc] + redbuf[576 + xr * 36 + xc]
                + redbuf[1152 + xr * 36 + xc] + redbuf[1728 + xr * 36 + xc] + cg2x;
      float g = tanhf(pre);
      int gc = cg * 32 + xc;
      int q = qv2;
      int hold = h2i[xr][gc];
      float zf = (float)q * (1.0f / 1024.0f);
      int ni = (int)rintf((1.0f - zf) * g * SCALE_F);
      int hnew = (hold >> 10) * q + (((hold & 1023) * q) >> 10) + ni;
      if (t >= lens[xr]) hnew = hold;
      st64(&ch[5][gc * 16 + xr], ((ull)tagp << 32) | (unsigned)hnew);
      if (L == 0)
        st64(&g_h0s[((size_t)t * 512 + 256 + gc) * 64 + rb0 + xr],
             ((ull)tagp << 32) | __float_as_uint((float)hnew * INV_S));
      if (t == 511) d_out[L * 32768 + (rb0 + xr) * 512 + 256 + gc] = hnew;
    }
    // EAGER sentinel; next step's GATE(3) barrier protects h2i/phi before
    // the next P1 staging overwrites them.
    if (tid == 0) st64(&g_sent[L][dm][3][cg], ((ull)tagp << 32) | 1u);

    if (L == 0) {
      cz1a = nz1a; cz1b = nz1b; cg1x = ng1x; cz2a = nz2a; cz2b = nz2b; cg2x = ng2x;
    }
  }
#undef GATE
#undef STAGE8
#undef DEP_SPLIT
#undef DEP_R
#undef SPLIT3Z
}

// ------------------------------------------------------------------
extern "C" void kernel_launch(void* const* d_in, const int* in_sizes, int n_in,
                              void* d_out, int out_size, void* d_ws, size_t ws_size,
                              hipStream_t stream) {
  const int*   seq     = (const int*)d_in[0];
  const int*   lengths = (const int*)d_in[1];
  const float* emb     = (const float*)d_in[2];
  const float* Wz1     = (const float*)d_in[3];
  const float* bz1     = (const float*)d_in[4];
  const float* Wg1     = (const float*)d_in[5];
  const float* bg1     = (const float*)d_in[6];
  const float* Wz2     = (const float*)d_in[7];
  const float* bz2     = (const float*)d_in[8];
  const float* Wg2     = (const float*)d_in[9];
  const float* bg2     = (const float*)d_in[10];
  int* out = (int*)d_out;
  (void)in_sizes; (void)n_in; (void)out_size; (void)d_ws; (void)ws_size;

  bump_epoch<<<1, 1, 0, stream>>>();
  prep_x<<<3072, 256, 0, stream>>>(Wz1, bz1, Wg1, bg1, Wz2, bz2, Wg2, bg2, 0, out, 1);
  prep_x<<<3072, 256, 0, stream>>>(Wz1, bz1, Wg1, bg1, Wz2, bz2, Wg2, bg2, 1, out, 0);
  gemmx_kernel<<<dim3(256, 12), 256, 0, stream>>>(seq, emb);
  fused_kernel<<<112, 512, 0, stream>>>(Wz1, Wg1, Wz2, Wg2, lengths, out);
}